// Round 4
// baseline (1860.817 us; speedup 1.0000x reference)
//
#include <hip/hip_runtime.h>
#include <math.h>

#define NN 50000
#define TT 4
#define FF 128
#define EE 800000
#define NBS 196   // scan blocks = ceil(NN/256)

#define EP_ZRH 0
#define EP_Z0  1
#define EP_GRU 2

typedef __attribute__((ext_vector_type(8))) short bf8_t;
typedef __attribute__((ext_vector_type(4))) float f4_t;
typedef __attribute__((ext_vector_type(8))) ushort us8;

__device__ inline ushort f2bf(float f){
  union { float f; unsigned u; } v; v.f = f;
  unsigned u = v.u;
  unsigned r = (u + 0x7fff + ((u>>16)&1)) >> 16;  // RNE
  return (ushort)r;
}
__device__ inline float lo16(unsigned u){ union{unsigned u;float f;}v; v.u=u<<16; return v.f; }
__device__ inline float hi16(unsigned u){ union{unsigned u;float f;}v; v.u=u&0xffff0000u; return v.f; }
__device__ inline unsigned packbf(float x, float y){
  return (unsigned)f2bf(x) | ((unsigned)f2bf(y)<<16);
}
__device__ inline float sigm(float x){ return 1.f/(1.f+expf(-x)); }

// ---------------- utility ----------------
__global__ void k_zero2i(int* __restrict__ a, int* __restrict__ b, int n){
  int i = blockIdx.x*256 + threadIdx.x;
  if(i<n){ a[i]=0; b[i]=0; }
}
__global__ void k_copy(const float* __restrict__ a, float* __restrict__ b, int n){
  int i = blockIdx.x*256 + threadIdx.x;
  if(i<n) b[i]=a[i];
}
__global__ void k_cast(const float* __restrict__ in, ushort* __restrict__ outp, int n4){
  int i = blockIdx.x*256 + threadIdx.x;
  if(i<n4){
    float4 v = ((const float4*)in)[i];
    ushort4 o; o.x=f2bf(v.x); o.y=f2bf(v.y); o.z=f2bf(v.z); o.w=f2bf(v.w);
    ((ushort4*)outp)[i]=o;
  }
}
// combined biases: bz=bxz+bhz, br=bxr+bhr, bh=bxh+bhh
__global__ void k_bias(const float* bxz, const float* bhz, const float* bxr,
                       const float* bhr, const float* bxh, const float* bhh,
                       float* __restrict__ bz, float* __restrict__ br, float* __restrict__ bh){
  int i = threadIdx.x;  // 384 threads
  int c = i & 127, s = i >> 7;
  if(s==0) bz[c]=bxz[c]+bhz[c];
  else if(s==1) br[c]=bxr[c]+bhr[c];
  else bh[c]=bxh[c]+bhh[c];
}

// count out-degree (src) for norm and in-degree (dst) for CSR
__global__ void k_count(const int* __restrict__ src, const int* __restrict__ dst,
                        int* __restrict__ deg, int* __restrict__ cnt){
  int i = blockIdx.x*256 + threadIdx.x;
  if(i<EE){ atomicAdd(&deg[src[i]],1); atomicAdd(&cnt[dst[i]],1); }
}

// ---------- hierarchical exclusive scan over cnt -> offs ----------
__global__ void k_scanA(const int* __restrict__ cnt, int* __restrict__ offs,
                        int* __restrict__ part){
  __shared__ int sd[256];
  int b = blockIdx.x, tid = threadIdx.x, i = b*256+tid;
  int c = (i<NN)?cnt[i]:0;
  sd[tid]=c; __syncthreads();
  for(int off=1;off<256;off<<=1){
    int v=(tid>=off)?sd[tid-off]:0; __syncthreads();
    sd[tid]+=v; __syncthreads();
  }
  if(i<NN) offs[i]=sd[tid]-c;
  if(tid==255) part[b]=sd[255];
}
__global__ void k_scanB(int* __restrict__ part){   // one block
  __shared__ int sd[256];
  int tid = threadIdx.x;
  int v = (tid<NBS)?part[tid]:0;
  sd[tid]=v; __syncthreads();
  for(int off=1;off<256;off<<=1){
    int t=(tid>=off)?sd[tid-off]:0; __syncthreads();
    sd[tid]+=t; __syncthreads();
  }
  if(tid<NBS) part[tid]=sd[tid]-v;
}
__global__ void k_scanC(const int* __restrict__ deg, int* __restrict__ offs,
                        const int* __restrict__ part, float* __restrict__ dinv,
                        int* __restrict__ cur){
  int i = blockIdx.x*256 + threadIdx.x;
  if(i<NN){
    offs[i] += part[blockIdx.x];
    int d = deg[i];
    dinv[i] = d>0 ? rsqrtf((float)d) : 0.f;
    cur[i]=0;
  }
  if(i==0) offs[NN]=EE;
}

// build dst-sorted CSR of packed (src, w) pairs
__global__ void k_scatter(const int* __restrict__ src, const int* __restrict__ dst,
                          const float* __restrict__ dinv, const int* __restrict__ offs,
                          int* __restrict__ cur, int2* __restrict__ meta){
  int i = blockIdx.x*256 + threadIdx.x;
  if(i<EE){
    int s=src[i], d=dst[i];
    float w = -dinv[s]*dinv[d];
    int pos = offs[d] + atomicAdd(&cur[d],1);
    int2 m; m.x=s; m.y=__float_as_int(w);
    meta[pos]=m;
  }
}

// -------- fused dual-input bf16 gather-SpMM --------
__global__ void k_spmm2(const int* __restrict__ offs, const int2* __restrict__ meta,
                        const ushort* __restrict__ Xa, const ushort* __restrict__ Xb,
                        const ushort* __restrict__ X0a, const ushort* __restrict__ X0b,
                        ushort* __restrict__ outA, ushort* __restrict__ outB){
  int wid = threadIdx.x>>6, lane = threadIdx.x&63;
  int row = blockIdx.x*4+wid;
  if(row>=NN) return;
  int beg = offs[row], end = offs[row+1];
  const unsigned* XA = (const unsigned*)Xa;
  const unsigned* XB = (const unsigned*)Xb;
  float ax=0.f, ay=0.f, bx=0.f, by=0.f;
  int e = beg;
  for(; e+3<end; e+=4){
    int2 p0=meta[e+0], p1=meta[e+1], p2=meta[e+2], p3=meta[e+3];
    float w0=__int_as_float(p0.y), w1=__int_as_float(p1.y);
    float w2=__int_as_float(p2.y), w3=__int_as_float(p3.y);
    unsigned a0=XA[p0.x*64+lane], a1=XA[p1.x*64+lane], a2=XA[p2.x*64+lane], a3=XA[p3.x*64+lane];
    unsigned b0=XB[p0.x*64+lane], b1=XB[p1.x*64+lane], b2=XB[p2.x*64+lane], b3=XB[p3.x*64+lane];
    ax=fmaf(w0,lo16(a0),ax); ay=fmaf(w0,hi16(a0),ay);
    ax=fmaf(w1,lo16(a1),ax); ay=fmaf(w1,hi16(a1),ay);
    ax=fmaf(w2,lo16(a2),ax); ay=fmaf(w2,hi16(a2),ay);
    ax=fmaf(w3,lo16(a3),ax); ay=fmaf(w3,hi16(a3),ay);
    bx=fmaf(w0,lo16(b0),bx); by=fmaf(w0,hi16(b0),by);
    bx=fmaf(w1,lo16(b1),bx); by=fmaf(w1,hi16(b1),by);
    bx=fmaf(w2,lo16(b2),bx); by=fmaf(w2,hi16(b2),by);
    bx=fmaf(w3,lo16(b3),bx); by=fmaf(w3,hi16(b3),by);
  }
  for(; e<end; ++e){
    int2 pm=meta[e]; float w=__int_as_float(pm.y);
    unsigned a=XA[pm.x*64+lane], b=XB[pm.x*64+lane];
    ax=fmaf(w,lo16(a),ax); ay=fmaf(w,hi16(a),ay);
    bx=fmaf(w,lo16(b),bx); by=fmaf(w,hi16(b),by);
  }
  int oi = row*64+lane;
  if(X0a){
    unsigned xa = ((const unsigned*)X0a)[oi];
    unsigned xb = ((const unsigned*)X0b)[oi];
    ax = 2.f*ax - lo16(xa); ay = 2.f*ay - hi16(xa);
    bx = 2.f*bx - lo16(xb); by = 2.f*by - hi16(xb);
  }
  ((unsigned*)outA)[oi] = packbf(ax, ay);
  ((unsigned*)outB)[oi] = packbf(bx, by);
}

// single-input variant
__global__ void k_spmm1(const int* __restrict__ offs, const int2* __restrict__ meta,
                        const ushort* __restrict__ Xa, const ushort* __restrict__ X0a,
                        ushort* __restrict__ outA){
  int wid = threadIdx.x>>6, lane = threadIdx.x&63;
  int row = blockIdx.x*4+wid;
  if(row>=NN) return;
  int beg = offs[row], end = offs[row+1];
  const unsigned* XA = (const unsigned*)Xa;
  float ax=0.f, ay=0.f;
  int e = beg;
  for(; e+3<end; e+=4){
    int2 p0=meta[e+0], p1=meta[e+1], p2=meta[e+2], p3=meta[e+3];
    float w0=__int_as_float(p0.y), w1=__int_as_float(p1.y);
    float w2=__int_as_float(p2.y), w3=__int_as_float(p3.y);
    unsigned a0=XA[p0.x*64+lane], a1=XA[p1.x*64+lane], a2=XA[p2.x*64+lane], a3=XA[p3.x*64+lane];
    ax=fmaf(w0,lo16(a0),ax); ay=fmaf(w0,hi16(a0),ay);
    ax=fmaf(w1,lo16(a1),ax); ay=fmaf(w1,hi16(a1),ay);
    ax=fmaf(w2,lo16(a2),ax); ay=fmaf(w2,hi16(a2),ay);
    ax=fmaf(w3,lo16(a3),ax); ay=fmaf(w3,hi16(a3),ay);
  }
  for(; e<end; ++e){
    int2 pm=meta[e]; float w=__int_as_float(pm.y);
    unsigned a=XA[pm.x*64+lane];
    ax=fmaf(w,lo16(a),ax); ay=fmaf(w,hi16(a),ay);
  }
  int oi = row*64+lane;
  if(X0a){
    unsigned xa = ((const unsigned*)X0a)[oi];
    ax = 2.f*ax - lo16(xa); ay = 2.f*ay - hi16(xa);
  }
  ((unsigned*)outA)[oi] = packbf(ax, ay);
}

// ---------------- MFMA bf16 GEMM with fused GRU epilogues ----------------
// A as up-to-6 chunks of 128 bf16 cols; Bt transposed [c][k] with row stride ldb.
// grid 1D: bm = bid/ngrp, g = bid%ngrp. 128x128 tile, BK=64, 4 waves.
__global__ __launch_bounds__(256) void k_mgemm(
    const ushort* __restrict__ A0, const ushort* __restrict__ A1,
    const ushort* __restrict__ A2, const ushort* __restrict__ A3,
    const ushort* __restrict__ A4, const ushort* __restrict__ A5,
    const ushort* __restrict__ Bt, int K, int ldb, int ngrp, int mode,
    const float* __restrict__ bz, const float* __restrict__ br, const float* __restrict__ bh,
    const float* __restrict__ H, const float* __restrict__ Zin,
    float* __restrict__ Zout, ushort* __restrict__ HRb, float* __restrict__ OXh,
    float* __restrict__ Hn, ushort* __restrict__ Hnb)
{
  __shared__ ushort As[128*64];
  __shared__ ushort Bs[128*64];
  int tid = threadIdx.x;
  int lane = tid & 63;
  int wid = tid >> 6;
  int wr = (wid>>1)*64, wc = (wid&1)*64;
  int bm = blockIdx.x / ngrp;
  int g  = blockIdx.x - bm*ngrp;
  int bn = (mode==EP_Z0) ? g*2 : g;
  f4_t acc[4][4] = {};
  int srow = tid>>3, sc = tid&7;
  int lr = lane&15, lk = lane>>4;
  int nkt = K>>6;
  for(int kt=0; kt<nkt; ++kt){
    int k0 = kt<<6;
    const ushort* Ac = (k0<128)?A0:(k0<256)?A1:(k0<384)?A2:(k0<512)?A3:(k0<640)?A4:A5;
    int kloc = k0 & 127;
    #pragma unroll
    for(int p=0;p<4;++p){
      int r = srow + p*32;
      int gr = bm*128 + r; if(gr>=NN) gr=NN-1;
      us8 av = *(const us8*)(Ac + (size_t)gr*128 + kloc + sc*8);
      us8 bv = *(const us8*)(Bt + (size_t)(bn*128 + r)*ldb + k0 + sc*8);
      int wo = (r*128 + ((sc*16) ^ ((r&7)<<4))) >> 1;
      *(us8*)(As + wo) = av;
      *(us8*)(Bs + wo) = bv;
    }
    __syncthreads();
    #pragma unroll
    for(int kk=0;kk<2;++kk){
      bf8_t af[4], bfr[4];
      int co = kk*64 + lk*16;
      #pragma unroll
      for(int m=0;m<4;++m){
        int Ra = wr + m*16 + lr;
        af[m]  = *(const bf8_t*)(As + ((Ra*128 + (co ^ ((Ra&7)<<4)))>>1));
        int Rb = wc + m*16 + lr;
        bfr[m] = *(const bf8_t*)(Bs + ((Rb*128 + (co ^ ((Rb&7)<<4)))>>1));
      }
      #pragma unroll
      for(int m=0;m<4;++m)
        #pragma unroll
        for(int n=0;n<4;++n)
          acc[m][n] = __builtin_amdgcn_mfma_f32_16x16x32_bf16(af[m], bfr[n], acc[m][n], 0,0,0);
    }
    __syncthreads();
  }
  // epilogue: D frag row=(lane>>4)*4+i, col=lane&15
  int row0 = bm*128 + wr + lk*4;
  int cl0  = wc + lr;
  #pragma unroll
  for(int m=0;m<4;++m){
    #pragma unroll
    for(int i=0;i<4;++i){
      int r = row0 + m*16 + i;
      if(r<NN){
        size_t base = (size_t)r*128;
        #pragma unroll
        for(int n=0;n<4;++n){
          int c = cl0 + n*16;
          float v = acc[m][n][i];
          if(mode==EP_ZRH){
            if(g==0)      Zout[base+c] = sigm(v + bz[c]);
            else if(g==1) HRb[base+c]  = f2bf(H[base+c] * sigm(v + br[c]));
            else          OXh[base+c]  = v;
          } else if(mode==EP_Z0){
            if(g==0) Zout[base+c] = sigm(v + bz[c]);
            else     OXh[base+c]  = v;
          } else {  // EP_GRU: full GRU combine
            float vv = v + OXh[base+c] + bh[c];
            float ht = tanhf(vv);
            float z  = Zin[base+c];
            float hn = z*H[base+c] + (1.f-z)*ht;
            Hn[base+c]  = hn;
            Hnb[base+c] = f2bf(hn);
          }
        }
      }
    }
  }
}

// t=0 tail: Hn = (1-Z)*tanh(OXh + bh)   (H == 0)
__global__ void k_gru0(const float* __restrict__ OXh, const float* __restrict__ Z,
                       const float* __restrict__ bh, float* __restrict__ Hn,
                       ushort* __restrict__ Hnb){
  int i = blockIdx.x*256 + threadIdx.x;
  if(i>=NN*FF) return;
  int c = i&127;
  float ht = tanhf(OXh[i] + bh[c]);
  float hn = (1.f - Z[i])*ht;
  Hn[i]=hn; Hnb[i]=f2bf(hn);
}

// fp32 GEMM for the (small) decoder
__global__ __launch_bounds__(256) void k_gemm(
    const float* __restrict__ A0, const float* __restrict__ B, float* __restrict__ C,
    int K, int Fo, int ldc, const float* __restrict__ bias, int act){
  __shared__ float Asq[64][17];
  __shared__ float Bsq[16][64];
  int tid = threadIdx.x;
  int tx = tid & 15, ty = tid >> 4;
  int bm = blockIdx.x, bn = blockIdx.y;
  float acc[4][4] = {{0.f}};
  int lr = tid>>2, lkv = tid&3;
  int lkk = tid>>4, lcv = tid&15;
  int arow = bm*64 + lr; if(arow >= NN) arow = NN-1;
  int nkb = K>>4;
  for(int kb=0; kb<nkb; ++kb){
    int koff = kb<<4;
    float4 av = *(const float4*)(A0 + arow*128 + koff + lkv*4);
    float4 bv = *(const float4*)(B + (koff+lkk)*Fo + bn*64 + lcv*4);
    Asq[lr][lkv*4+0]=av.x; Asq[lr][lkv*4+1]=av.y; Asq[lr][lkv*4+2]=av.z; Asq[lr][lkv*4+3]=av.w;
    *(float4*)(&Bsq[lkk][lcv*4]) = bv;
    __syncthreads();
    #pragma unroll
    for(int kk=0;kk<16;++kk){
      float a0=Asq[ty*4+0][kk], a1=Asq[ty*4+1][kk], a2=Asq[ty*4+2][kk], a3=Asq[ty*4+3][kk];
      float4 b = *(const float4*)(&Bsq[kk][tx*4]);
      acc[0][0]=fmaf(a0,b.x,acc[0][0]); acc[0][1]=fmaf(a0,b.y,acc[0][1]);
      acc[0][2]=fmaf(a0,b.z,acc[0][2]); acc[0][3]=fmaf(a0,b.w,acc[0][3]);
      acc[1][0]=fmaf(a1,b.x,acc[1][0]); acc[1][1]=fmaf(a1,b.y,acc[1][1]);
      acc[1][2]=fmaf(a1,b.z,acc[1][2]); acc[1][3]=fmaf(a1,b.w,acc[1][3]);
      acc[2][0]=fmaf(a2,b.x,acc[2][0]); acc[2][1]=fmaf(a2,b.y,acc[2][1]);
      acc[2][2]=fmaf(a2,b.z,acc[2][2]); acc[2][3]=fmaf(a2,b.w,acc[2][3]);
      acc[3][0]=fmaf(a3,b.x,acc[3][0]); acc[3][1]=fmaf(a3,b.y,acc[3][1]);
      acc[3][2]=fmaf(a3,b.z,acc[3][2]); acc[3][3]=fmaf(a3,b.w,acc[3][3]);
    }
    __syncthreads();
  }
  int row0 = bm*64 + ty*4;
  int col  = bn*64 + tx*4;
  #pragma unroll
  for(int i=0;i<4;++i){
    int r = row0+i;
    if(r<NN){
      float4 v; v.x=acc[i][0]; v.y=acc[i][1]; v.z=acc[i][2]; v.w=acc[i][3];
      if(bias){ v.x+=bias[col]; v.y+=bias[col+1]; v.z+=bias[col+2]; v.w+=bias[col+3]; }
      if(act){ v.x=fmaxf(v.x,0.f); v.y=fmaxf(v.y,0.f); v.z=fmaxf(v.z,0.f); v.w=fmaxf(v.w,0.f); }
      float* cp = C + r*ldc + col;
      *(float4*)cp = v;
    }
  }
}

// pack x-side weights transposed+concatenated: Btx[c][k], c in [0,384), k in [0,768)
__global__ void k_packx(const float* __restrict__ Wxz, const float* __restrict__ Wxr,
                        const float* __restrict__ Wxh, const float* __restrict__ Whz,
                        const float* __restrict__ Whr, ushort* __restrict__ Bt){
  int i = blockIdx.x*256 + threadIdx.x;
  if(i>=384*768) return;
  int c = i/768, k = i - c*768;
  int g = c>>7, j = c&127;
  int kb = k>>7, kk = k&127;
  float v;
  if(kb<3){
    const float* W = (g==0)?Wxz:((g==1)?Wxr:Wxh);
    v = W[(kb*128+kk)*128 + j];
  } else if(g<2){
    const float* W = (g==0)?Whz:Whr;
    v = W[((kb-3)*128+kk)*128 + j];
  } else v = 0.f;
  Bt[i] = f2bf(v);
}
// Bth[c][k] = Whh[k>>7][k&127][c], c<128, k<384
__global__ void k_packh(const float* __restrict__ Whh, ushort* __restrict__ Bt){
  int i = blockIdx.x*256 + threadIdx.x;
  if(i>=128*384) return;
  int c = i/384, k = i - c*384;
  Bt[i] = f2bf(Whh[((k>>7)*128 + (k&127))*128 + c]);
}

extern "C" void kernel_launch(void* const* d_in, const int* in_sizes, int n_in,
                              void* d_out, int out_size, void* d_ws, size_t ws_size,
                              hipStream_t stream) {
  const float* x   = (const float*)d_in[0];
  const int*   ei  = (const int*)d_in[1];
  const float* Wxz = (const float*)d_in[2];
  const float* Whz = (const float*)d_in[3];
  const float* Wxr = (const float*)d_in[4];
  const float* Whr = (const float*)d_in[5];
  const float* Wxh = (const float*)d_in[6];
  const float* Whh = (const float*)d_in[7];
  const float* bxz = (const float*)d_in[8];
  const float* bhz = (const float*)d_in[9];
  const float* bxr = (const float*)d_in[10];
  const float* bhr = (const float*)d_in[11];
  const float* bxh = (const float*)d_in[12];
  const float* bhh = (const float*)d_in[13];
  const float* Wd1 = (const float*)d_in[14];
  const float* bd1 = (const float*)d_in[15];
  const float* Wd2 = (const float*)d_in[16];
  const float* bd2 = (const float*)d_in[17];
  float* out = (float*)d_out;

  char* p = (char*)d_ws;
  auto alloc = [&](size_t bytes)->void*{ void* r = (void*)p; p += (bytes+255)&~(size_t)255; return r; };
  const size_t NFB  = (size_t)NN*FF*4;
  const size_t NFB2 = (size_t)NN*FF*2;
  float* Ha   = (float*)alloc(NFB);
  float* Hb   = (float*)alloc(NFB);
  float* Zb   = (float*)alloc(NFB);
  float* OXh  = (float*)alloc(NFB);
  float* Dt   = (float*)alloc(NFB);      // decoder temp
  ushort* xtb = (ushort*)alloc(NFB2);
  ushort* A1b = (ushort*)alloc(NFB2);
  ushort* A2b = (ushort*)alloc(NFB2);
  ushort* A3b = (ushort*)alloc(NFB2);
  ushort* A4b = (ushort*)alloc(NFB2);
  ushort* HRb = (ushort*)alloc(NFB2);
  ushort* Hab = (ushort*)alloc(NFB2);
  ushort* Hbb = (ushort*)alloc(NFB2);
  ushort* Btx = (ushort*)alloc((size_t)384*768*2);
  ushort* Bth = (ushort*)alloc((size_t)128*384*2);
  float* bzc  = (float*)alloc(128*4);
  float* brc  = (float*)alloc(128*4);
  float* bhc  = (float*)alloc(128*4);
  float* dinv = (float*)alloc((size_t)NN*4);
  int* deg  = (int*)alloc((size_t)NN*4);
  int* cnt  = (int*)alloc((size_t)NN*4);
  int* cur  = (int*)alloc((size_t)NN*4);
  int* offs = (int*)alloc((size_t)(NN+1)*4);
  int* part = (int*)alloc((size_t)256*4);
  int2* meta = (int2*)alloc((size_t)EE*8);

  const int eb = (EE+255)/256;
  const int nb = NBS;
  const int fb = (NN*FF+255)/256;
  const int sg = (NN+3)/4;
  const int MT = (NN+127)/128;  // 391

  k_packx<<<(384*768+255)/256,256,0,stream>>>(Wxz,Wxr,Wxh,Whz,Whr,Btx);
  k_packh<<<(128*384+255)/256,256,0,stream>>>(Whh,Bth);
  k_bias<<<1,384,0,stream>>>(bxz,bhz,bxr,bhr,bxh,bhh,bzc,brc,bhc);

  float* Hc = Ha; float* Hn = Hb;
  ushort* Hcb = Hab; ushort* Hnb = Hbb;
  for(int t=0;t<TT;++t){
    const float* xt = x + (size_t)t*NN*FF;
    const int* src = ei + (size_t)t*2*EE;
    const int* dst = src + EE;
    k_cast<<<(NN*FF/4+255)/256,256,0,stream>>>(xt, xtb, NN*FF/4);
    k_zero2i<<<nb,256,0,stream>>>(deg,cnt,NN);
    k_count<<<eb,256,0,stream>>>(src,dst,deg,cnt);
    k_scanA<<<nb,256,0,stream>>>(cnt,offs,part);
    k_scanB<<<1,256,0,stream>>>(part);
    k_scanC<<<nb,256,0,stream>>>(deg,offs,part,dinv,cur);
    k_scatter<<<eb,256,0,stream>>>(src,dst,dinv,offs,cur,meta);
    if(t==0){
      // H == 0: x-path only; no gate-r / HR work at all
      k_spmm1<<<sg,256,0,stream>>>(offs,meta, xtb, nullptr, A1b);
      k_spmm1<<<sg,256,0,stream>>>(offs,meta, A1b, xtb,     A2b);
      k_mgemm<<<MT*2,256,0,stream>>>(xtb,A1b,A2b,nullptr,nullptr,nullptr,
          Btx, 384, 768, 2, EP_Z0, bzc,brc,bhc, nullptr,nullptr,
          Zb, nullptr, OXh, nullptr, nullptr);
      k_gru0<<<fb,256,0,stream>>>(OXh, Zb, bhc, Hn, Hnb);
    } else {
      k_spmm2<<<sg,256,0,stream>>>(offs,meta, xtb,Hcb, nullptr,nullptr, A1b,A3b);
      k_spmm2<<<sg,256,0,stream>>>(offs,meta, A1b,A3b, xtb,Hcb,         A2b,A4b);
      // K=768 x+H GEMM, epilogue computes Z / HRb / OXh per column-block
      k_mgemm<<<MT*3,256,0,stream>>>(xtb,A1b,A2b,Hcb,A3b,A4b,
          Btx, 768, 768, 3, EP_ZRH, bzc,brc,bhc, Hc,nullptr,
          Zb, HRb, OXh, nullptr, nullptr);
      // HR-path propagation + K=384 GEMM with full GRU-combine epilogue
      k_spmm1<<<sg,256,0,stream>>>(offs,meta, HRb, nullptr, A3b);
      k_spmm1<<<sg,256,0,stream>>>(offs,meta, A3b, HRb,     A4b);
      k_mgemm<<<MT,256,0,stream>>>(HRb,A3b,A4b,nullptr,nullptr,nullptr,
          Bth, 384, 384, 1, EP_GRU, bzc,brc,bhc, Hc,Zb,
          nullptr, nullptr, OXh, Hn, Hnb);
    }
    float* tmp=Hc; Hc=Hn; Hn=tmp;
    ushort* tb=Hcb; Hcb=Hnb; Hnb=tb;
  }
  // decoder: x_pred = relu(H@Wd1+bd1)@Wd2+bd2  (fp32)
  dim3 gd((NN+63)/64, 2);
  k_gemm<<<gd,256,0,stream>>>(Hc, Wd1, Dt, 128, 128, 128, bd1, 1);
  k_gemm<<<gd,256,0,stream>>>(Dt, Wd2, out, 128, 128, 128, bd2, 0);
  k_copy<<<fb,256,0,stream>>>(Hc, out + (size_t)NN*FF, NN*FF);
}

// Round 5
// 1594.235 us; speedup vs baseline: 1.1672x; 1.1672x over previous
//
#include <hip/hip_runtime.h>
#include <math.h>

#define NN 50000
#define TT 4
#define FF 128
#define EE 800000
#define NBS 196   // scan blocks = ceil(NN/256)

typedef __attribute__((ext_vector_type(8))) short bf8_t;
typedef __attribute__((ext_vector_type(4))) float f4_t;
typedef __attribute__((ext_vector_type(8))) ushort us8;

__device__ inline ushort f2bf(float f){
  union { float f; unsigned u; } v; v.f = f;
  unsigned u = v.u;
  unsigned r = (u + 0x7fff + ((u>>16)&1)) >> 16;  // RNE
  return (ushort)r;
}
__device__ inline float lo16(unsigned u){ union{unsigned u;float f;}v; v.u=u<<16; return v.f; }
__device__ inline float hi16(unsigned u){ union{unsigned u;float f;}v; v.u=u&0xffff0000u; return v.f; }
__device__ inline unsigned packbf(float x, float y){
  return (unsigned)f2bf(x) | ((unsigned)f2bf(y)<<16);
}
__device__ inline float sigm(float x){ return 1.f/(1.f+expf(-x)); }

// ---------------- utility ----------------
__global__ void k_zero_i(int* __restrict__ a, int n){
  int i = blockIdx.x*256 + threadIdx.x;
  if(i<n) a[i]=0;
}
__global__ void k_copy(const float* __restrict__ a, float* __restrict__ b, int n){
  int i = blockIdx.x*256 + threadIdx.x;
  if(i<n) b[i]=a[i];
}
// cast all T snapshots at once
__global__ void k_cast4(const float* __restrict__ in, ushort* __restrict__ outp, int n4){
  int i = blockIdx.x*256 + threadIdx.x;
  if(i<n4){
    float4 v = ((const float4*)in)[i];
    ushort4 o; o.x=f2bf(v.x); o.y=f2bf(v.y); o.z=f2bf(v.z); o.w=f2bf(v.w);
    ((ushort4*)outp)[i]=o;
  }
}
// combined biases: bz=bxz+bhz, br=bxr+bhr, bh=bxh+bhh
__global__ void k_bias(const float* bxz, const float* bhz, const float* bxr,
                       const float* bhr, const float* bxh, const float* bhh,
                       float* __restrict__ bz, float* __restrict__ br, float* __restrict__ bh){
  int i = threadIdx.x;  // 384 threads
  int c = i & 127, s = i >> 7;
  if(s==0) bz[c]=bxz[c]+bhz[c];
  else if(s==1) br[c]=bxr[c]+bhr[c];
  else bh[c]=bxh[c]+bhh[c];
}

// ---------- batched CSR build (blockIdx.y = t) ----------
__global__ void k_count4(const int* __restrict__ ei, int* __restrict__ deg4,
                         int* __restrict__ cnt4){
  int t = blockIdx.y;
  int i = blockIdx.x*256 + threadIdx.x;
  const int* src = ei + (size_t)t*2*EE;
  const int* dst = src + EE;
  int* deg = deg4 + (size_t)t*NN;
  int* cnt = cnt4 + (size_t)t*NN;
  if(i<EE){ atomicAdd(&deg[src[i]],1); atomicAdd(&cnt[dst[i]],1); }
}
__global__ void k_scanA(const int* __restrict__ cnt4, int* __restrict__ offs4,
                        int* __restrict__ part4){
  int t = blockIdx.y;
  const int* cnt = cnt4 + (size_t)t*NN;
  int* offs = offs4 + (size_t)t*(NN+1);
  int* part = part4 + (size_t)t*256;
  __shared__ int sd[256];
  int b = blockIdx.x, tid = threadIdx.x, i = b*256+tid;
  int c = (i<NN)?cnt[i]:0;
  sd[tid]=c; __syncthreads();
  for(int off=1;off<256;off<<=1){
    int v=(tid>=off)?sd[tid-off]:0; __syncthreads();
    sd[tid]+=v; __syncthreads();
  }
  if(i<NN) offs[i]=sd[tid]-c;
  if(tid==255) part[b]=sd[255];
}
__global__ void k_scanB(int* __restrict__ part4){   // 4 blocks
  int* part = part4 + (size_t)blockIdx.x*256;
  __shared__ int sd[256];
  int tid = threadIdx.x;
  int v = (tid<NBS)?part[tid]:0;
  sd[tid]=v; __syncthreads();
  for(int off=1;off<256;off<<=1){
    int t=(tid>=off)?sd[tid-off]:0; __syncthreads();
    sd[tid]+=t; __syncthreads();
  }
  if(tid<NBS) part[tid]=sd[tid]-v;
}
__global__ void k_scanC(const int* __restrict__ deg4, int* __restrict__ offs4,
                        const int* __restrict__ part4, float* __restrict__ dinv4,
                        int* __restrict__ cur4){
  int t = blockIdx.y;
  const int* deg = deg4 + (size_t)t*NN;
  int* offs = offs4 + (size_t)t*(NN+1);
  const int* part = part4 + (size_t)t*256;
  float* dinv = dinv4 + (size_t)t*NN;
  int* cur = cur4 + (size_t)t*NN;
  int i = blockIdx.x*256 + threadIdx.x;
  if(i<NN){
    offs[i] += part[blockIdx.x];
    int d = deg[i];
    dinv[i] = d>0 ? rsqrtf((float)d) : 0.f;
    cur[i]=0;
  }
  if(i==0) offs[NN]=EE;
}
__global__ void k_scatter4(const int* __restrict__ ei, const float* __restrict__ dinv4,
                           const int* __restrict__ offs4, int* __restrict__ cur4,
                           int2* __restrict__ meta4){
  int t = blockIdx.y;
  int i = blockIdx.x*256 + threadIdx.x;
  const int* src = ei + (size_t)t*2*EE;
  const int* dst = src + EE;
  const float* dinv = dinv4 + (size_t)t*NN;
  const int* offs = offs4 + (size_t)t*(NN+1);
  int* cur = cur4 + (size_t)t*NN;
  int2* meta = meta4 + (size_t)t*EE;
  if(i<EE){
    int s=src[i], d=dst[i];
    float w = -dinv[s]*dinv[d];
    int pos = offs[d] + atomicAdd(&cur[d],1);
    int2 m; m.x=s; m.y=__float_as_int(w);
    meta[pos]=m;
  }
}

// -------- fused dual-input bf16 gather-SpMM --------
__global__ void k_spmm2(const int* __restrict__ offs, const int2* __restrict__ meta,
                        const ushort* __restrict__ Xa, const ushort* __restrict__ Xb,
                        const ushort* __restrict__ X0a, const ushort* __restrict__ X0b,
                        ushort* __restrict__ outA, ushort* __restrict__ outB){
  int wid = threadIdx.x>>6, lane = threadIdx.x&63;
  int row = blockIdx.x*4+wid;
  if(row>=NN) return;
  int beg = offs[row], end = offs[row+1];
  const unsigned* XA = (const unsigned*)Xa;
  const unsigned* XB = (const unsigned*)Xb;
  float ax=0.f, ay=0.f, bx=0.f, by=0.f;
  int e = beg;
  for(; e+3<end; e+=4){
    int2 p0=meta[e+0], p1=meta[e+1], p2=meta[e+2], p3=meta[e+3];
    float w0=__int_as_float(p0.y), w1=__int_as_float(p1.y);
    float w2=__int_as_float(p2.y), w3=__int_as_float(p3.y);
    unsigned a0=XA[p0.x*64+lane], a1=XA[p1.x*64+lane], a2=XA[p2.x*64+lane], a3=XA[p3.x*64+lane];
    unsigned b0=XB[p0.x*64+lane], b1=XB[p1.x*64+lane], b2=XB[p2.x*64+lane], b3=XB[p3.x*64+lane];
    ax=fmaf(w0,lo16(a0),ax); ay=fmaf(w0,hi16(a0),ay);
    ax=fmaf(w1,lo16(a1),ax); ay=fmaf(w1,hi16(a1),ay);
    ax=fmaf(w2,lo16(a2),ax); ay=fmaf(w2,hi16(a2),ay);
    ax=fmaf(w3,lo16(a3),ax); ay=fmaf(w3,hi16(a3),ay);
    bx=fmaf(w0,lo16(b0),bx); by=fmaf(w0,hi16(b0),by);
    bx=fmaf(w1,lo16(b1),bx); by=fmaf(w1,hi16(b1),by);
    bx=fmaf(w2,lo16(b2),bx); by=fmaf(w2,hi16(b2),by);
    bx=fmaf(w3,lo16(b3),bx); by=fmaf(w3,hi16(b3),by);
  }
  for(; e<end; ++e){
    int2 pm=meta[e]; float w=__int_as_float(pm.y);
    unsigned a=XA[pm.x*64+lane], b=XB[pm.x*64+lane];
    ax=fmaf(w,lo16(a),ax); ay=fmaf(w,hi16(a),ay);
    bx=fmaf(w,lo16(b),bx); by=fmaf(w,hi16(b),by);
  }
  int oi = row*64+lane;
  if(X0a){
    unsigned xa = ((const unsigned*)X0a)[oi];
    unsigned xb = ((const unsigned*)X0b)[oi];
    ax = 2.f*ax - lo16(xa); ay = 2.f*ay - hi16(xa);
    bx = 2.f*bx - lo16(xb); by = 2.f*by - hi16(xb);
  }
  ((unsigned*)outA)[oi] = packbf(ax, ay);
  ((unsigned*)outB)[oi] = packbf(bx, by);
}

// single-input variant
__global__ void k_spmm1(const int* __restrict__ offs, const int2* __restrict__ meta,
                        const ushort* __restrict__ Xa, const ushort* __restrict__ X0a,
                        ushort* __restrict__ outA){
  int wid = threadIdx.x>>6, lane = threadIdx.x&63;
  int row = blockIdx.x*4+wid;
  if(row>=NN) return;
  int beg = offs[row], end = offs[row+1];
  const unsigned* XA = (const unsigned*)Xa;
  float ax=0.f, ay=0.f;
  int e = beg;
  for(; e+3<end; e+=4){
    int2 p0=meta[e+0], p1=meta[e+1], p2=meta[e+2], p3=meta[e+3];
    float w0=__int_as_float(p0.y), w1=__int_as_float(p1.y);
    float w2=__int_as_float(p2.y), w3=__int_as_float(p3.y);
    unsigned a0=XA[p0.x*64+lane], a1=XA[p1.x*64+lane], a2=XA[p2.x*64+lane], a3=XA[p3.x*64+lane];
    ax=fmaf(w0,lo16(a0),ax); ay=fmaf(w0,hi16(a0),ay);
    ax=fmaf(w1,lo16(a1),ax); ay=fmaf(w1,hi16(a1),ay);
    ax=fmaf(w2,lo16(a2),ax); ay=fmaf(w2,hi16(a2),ay);
    ax=fmaf(w3,lo16(a3),ax); ay=fmaf(w3,hi16(a3),ay);
  }
  for(; e<end; ++e){
    int2 pm=meta[e]; float w=__int_as_float(pm.y);
    unsigned a=XA[pm.x*64+lane];
    ax=fmaf(w,lo16(a),ax); ay=fmaf(w,hi16(a),ay);
  }
  int oi = row*64+lane;
  if(X0a){
    unsigned xa = ((const unsigned*)X0a)[oi];
    ax = 2.f*ax - lo16(xa); ay = 2.f*ay - hi16(xa);
  }
  ((unsigned*)outA)[oi] = packbf(ax, ay);
}

// ---------------- MFMA bf16 GEMM (R3 structure: plain OX store, 2D grid) ----------------
// A as up-to-6 chunks of 128 bf16 cols; Bt transposed [c][k], row stride ldb.
// bn = blockIdx.y * bnstep. C is [NN][384] fp32; write cols coloff + bn*128 .. +127.
__global__ __launch_bounds__(256) void k_mgemm(
    const ushort* __restrict__ A0, const ushort* __restrict__ A1,
    const ushort* __restrict__ A2, const ushort* __restrict__ A3,
    const ushort* __restrict__ A4, const ushort* __restrict__ A5,
    const ushort* __restrict__ Bt, float* __restrict__ C,
    int K, int ldb, int bnstep, int coloff, int beta)
{
  __shared__ ushort As[128*64];
  __shared__ ushort Bs[128*64];
  int tid = threadIdx.x;
  int lane = tid & 63;
  int wid = tid >> 6;
  int wr = (wid>>1)*64, wc = (wid&1)*64;
  int bm = blockIdx.x;
  int bn = blockIdx.y * bnstep;
  f4_t acc[4][4] = {};
  int srow = tid>>3, sc = tid&7;
  int lr = lane&15, lk = lane>>4;
  int nkt = K>>6;
  for(int kt=0; kt<nkt; ++kt){
    int k0 = kt<<6;
    const ushort* Ac = (k0<128)?A0:(k0<256)?A1:(k0<384)?A2:(k0<512)?A3:(k0<640)?A4:A5;
    int kloc = k0 & 127;
    #pragma unroll
    for(int p=0;p<4;++p){
      int r = srow + p*32;
      int gr = bm*128 + r; if(gr>=NN) gr=NN-1;
      us8 av = *(const us8*)(Ac + (size_t)gr*128 + kloc + sc*8);
      us8 bv = *(const us8*)(Bt + (size_t)(bn*128 + r)*ldb + k0 + sc*8);
      int wo = (r*128 + ((sc*16) ^ ((r&7)<<4))) >> 1;
      *(us8*)(As + wo) = av;
      *(us8*)(Bs + wo) = bv;
    }
    __syncthreads();
    #pragma unroll
    for(int kk=0;kk<2;++kk){
      bf8_t af[4], bfr[4];
      int co = kk*64 + lk*16;
      #pragma unroll
      for(int m=0;m<4;++m){
        int Ra = wr + m*16 + lr;
        af[m]  = *(const bf8_t*)(As + ((Ra*128 + (co ^ ((Ra&7)<<4)))>>1));
        int Rb = wc + m*16 + lr;
        bfr[m] = *(const bf8_t*)(Bs + ((Rb*128 + (co ^ ((Rb&7)<<4)))>>1));
      }
      #pragma unroll
      for(int m=0;m<4;++m)
        #pragma unroll
        for(int n=0;n<4;++n)
          acc[m][n] = __builtin_amdgcn_mfma_f32_16x16x32_bf16(af[m], bfr[n], acc[m][n], 0,0,0);
    }
    __syncthreads();
  }
  int row0 = bm*128 + wr + lk*4;
  int col0 = coloff + bn*128 + wc + lr;
  #pragma unroll
  for(int m=0;m<4;++m){
    #pragma unroll
    for(int i=0;i<4;++i){
      int r = row0 + m*16 + i;
      if(r<NN){
        float* cp = C + (size_t)r*384 + col0;
        #pragma unroll
        for(int n=0;n<4;++n){
          float v = acc[m][n][i];
          if(beta) v += cp[n*16];
          cp[n*16] = v;
        }
      }
    }
  }
}

// Z = sigmoid(OX[:,0:128]+bz); HRb = bf16(H * sigmoid(OX[:,128:256]+br))
__global__ void k_combA(const float* __restrict__ OX, const float* __restrict__ H,
                        const float* __restrict__ bz, const float* __restrict__ br,
                        float* __restrict__ Z, ushort* __restrict__ HRb){
  int i = blockIdx.x*256 + threadIdx.x;
  if(i>=NN*FF) return;
  int r = i>>7, c = i&127;
  float zv = sigm(OX[r*384+c]     + bz[c]);
  float rv = sigm(OX[r*384+128+c] + br[c]);
  float hr = H[i]*rv;
  Z[i]=zv; HRb[i]=f2bf(hr);
}

// Htilde = tanh(OX[:,256:384]+bh); Hnew = Z*H + (1-Z)*Htilde
__global__ void k_combB(const float* __restrict__ OX, const float* __restrict__ Z,
                        const float* __restrict__ H, const float* __restrict__ bh,
                        float* __restrict__ Hn, ushort* __restrict__ Hnb){
  int i = blockIdx.x*256 + threadIdx.x;
  if(i>=NN*FF) return;
  int r = i>>7, c = i&127;
  float ht = tanhf(OX[r*384+256+c] + bh[c]);
  float z = Z[i];
  float hn = z*H[i] + (1.f-z)*ht;
  Hn[i] = hn; Hnb[i] = f2bf(hn);
}

// t=0 tail (H==0): Hn = (1 - sigm(OXz+bz)) * tanh(OXh+bh)
__global__ void k_gru0(const float* __restrict__ OX, const float* __restrict__ bz,
                       const float* __restrict__ bh, float* __restrict__ Hn,
                       ushort* __restrict__ Hnb){
  int i = blockIdx.x*256 + threadIdx.x;
  if(i>=NN*FF) return;
  int r = i>>7, c = i&127;
  float z  = sigm(OX[r*384+c] + bz[c]);
  float ht = tanhf(OX[r*384+256+c] + bh[c]);
  float hn = (1.f - z)*ht;
  Hn[i]=hn; Hnb[i]=f2bf(hn);
}

// fp32 GEMM for the (small) decoder
__global__ __launch_bounds__(256) void k_gemm(
    const float* __restrict__ A0, const float* __restrict__ B, float* __restrict__ C,
    int K, int Fo, int ldc, const float* __restrict__ bias, int act){
  __shared__ float Asq[64][17];
  __shared__ float Bsq[16][64];
  int tid = threadIdx.x;
  int tx = tid & 15, ty = tid >> 4;
  int bm = blockIdx.x, bn = blockIdx.y;
  float acc[4][4] = {{0.f}};
  int lr = tid>>2, lkv = tid&3;
  int lkk = tid>>4, lcv = tid&15;
  int arow = bm*64 + lr; if(arow >= NN) arow = NN-1;
  int nkb = K>>4;
  for(int kb=0; kb<nkb; ++kb){
    int koff = kb<<4;
    float4 av = *(const float4*)(A0 + arow*128 + koff + lkv*4);
    float4 bv = *(const float4*)(B + (koff+lkk)*Fo + bn*64 + lcv*4);
    Asq[lr][lkv*4+0]=av.x; Asq[lr][lkv*4+1]=av.y; Asq[lr][lkv*4+2]=av.z; Asq[lr][lkv*4+3]=av.w;
    *(float4*)(&Bsq[lkk][lcv*4]) = bv;
    __syncthreads();
    #pragma unroll
    for(int kk=0;kk<16;++kk){
      float a0=Asq[ty*4+0][kk], a1=Asq[ty*4+1][kk], a2=Asq[ty*4+2][kk], a3=Asq[ty*4+3][kk];
      float4 b = *(const float4*)(&Bsq[kk][tx*4]);
      acc[0][0]=fmaf(a0,b.x,acc[0][0]); acc[0][1]=fmaf(a0,b.y,acc[0][1]);
      acc[0][2]=fmaf(a0,b.z,acc[0][2]); acc[0][3]=fmaf(a0,b.w,acc[0][3]);
      acc[1][0]=fmaf(a1,b.x,acc[1][0]); acc[1][1]=fmaf(a1,b.y,acc[1][1]);
      acc[1][2]=fmaf(a1,b.z,acc[1][2]); acc[1][3]=fmaf(a1,b.w,acc[1][3]);
      acc[2][0]=fmaf(a2,b.x,acc[2][0]); acc[2][1]=fmaf(a2,b.y,acc[2][1]);
      acc[2][2]=fmaf(a2,b.z,acc[2][2]); acc[2][3]=fmaf(a2,b.w,acc[2][3]);
      acc[3][0]=fmaf(a3,b.x,acc[3][0]); acc[3][1]=fmaf(a3,b.y,acc[3][1]);
      acc[3][2]=fmaf(a3,b.z,acc[3][2]); acc[3][3]=fmaf(a3,b.w,acc[3][3]);
    }
    __syncthreads();
  }
  int row0 = bm*64 + ty*4;
  int col  = bn*64 + tx*4;
  #pragma unroll
  for(int i=0;i<4;++i){
    int r = row0+i;
    if(r<NN){
      float4 v; v.x=acc[i][0]; v.y=acc[i][1]; v.z=acc[i][2]; v.w=acc[i][3];
      if(bias){ v.x+=bias[col]; v.y+=bias[col+1]; v.z+=bias[col+2]; v.w+=bias[col+3]; }
      if(act){ v.x=fmaxf(v.x,0.f); v.y=fmaxf(v.y,0.f); v.z=fmaxf(v.z,0.f); v.w=fmaxf(v.w,0.f); }
      float* cp = C + r*ldc + col;
      *(float4*)cp = v;
    }
  }
}

// pack x-side weights transposed+concatenated: Btx[c][k], c in [0,384), k in [0,768)
__global__ void k_packx(const float* __restrict__ Wxz, const float* __restrict__ Wxr,
                        const float* __restrict__ Wxh, const float* __restrict__ Whz,
                        const float* __restrict__ Whr, ushort* __restrict__ Bt){
  int i = blockIdx.x*256 + threadIdx.x;
  if(i>=384*768) return;
  int c = i/768, k = i - c*768;
  int g = c>>7, j = c&127;
  int kb = k>>7, kk = k&127;
  float v;
  if(kb<3){
    const float* W = (g==0)?Wxz:((g==1)?Wxr:Wxh);
    v = W[(kb*128+kk)*128 + j];
  } else if(g<2){
    const float* W = (g==0)?Whz:Whr;
    v = W[((kb-3)*128+kk)*128 + j];
  } else v = 0.f;
  Bt[i] = f2bf(v);
}
// Bth[c][k] = Whh[k>>7][k&127][c], c<128, k<384
__global__ void k_packh(const float* __restrict__ Whh, ushort* __restrict__ Bt){
  int i = blockIdx.x*256 + threadIdx.x;
  if(i>=128*384) return;
  int c = i/384, k = i - c*384;
  Bt[i] = f2bf(Whh[((k>>7)*128 + (k&127))*128 + c]);
}

extern "C" void kernel_launch(void* const* d_in, const int* in_sizes, int n_in,
                              void* d_out, int out_size, void* d_ws, size_t ws_size,
                              hipStream_t stream) {
  const float* x   = (const float*)d_in[0];
  const int*   ei  = (const int*)d_in[1];
  const float* Wxz = (const float*)d_in[2];
  const float* Whz = (const float*)d_in[3];
  const float* Wxr = (const float*)d_in[4];
  const float* Whr = (const float*)d_in[5];
  const float* Wxh = (const float*)d_in[6];
  const float* Whh = (const float*)d_in[7];
  const float* bxz = (const float*)d_in[8];
  const float* bhz = (const float*)d_in[9];
  const float* bxr = (const float*)d_in[10];
  const float* bhr = (const float*)d_in[11];
  const float* bxh = (const float*)d_in[12];
  const float* bhh = (const float*)d_in[13];
  const float* Wd1 = (const float*)d_in[14];
  const float* bd1 = (const float*)d_in[15];
  const float* Wd2 = (const float*)d_in[16];
  const float* bd2 = (const float*)d_in[17];
  float* out = (float*)d_out;

  char* p = (char*)d_ws;
  auto alloc = [&](size_t bytes)->void*{ void* r = (void*)p; p += (bytes+255)&~(size_t)255; return r; };
  const size_t NFB  = (size_t)NN*FF*4;
  const size_t NFB2 = (size_t)NN*FF*2;
  float* Ha   = (float*)alloc(NFB);
  float* Hb   = (float*)alloc(NFB);
  float* OX   = (float*)alloc((size_t)NN*384*4);  // also decoder temp
  float* Zb   = (float*)alloc(NFB);
  ushort* xtb4= (ushort*)alloc(NFB2*TT);          // all 4 casted snapshots
  ushort* A1b = (ushort*)alloc(NFB2);
  ushort* A2b = (ushort*)alloc(NFB2);
  ushort* A3b = (ushort*)alloc(NFB2);
  ushort* A4b = (ushort*)alloc(NFB2);
  ushort* HRb = (ushort*)alloc(NFB2);
  ushort* Hab = (ushort*)alloc(NFB2);
  ushort* Hbb = (ushort*)alloc(NFB2);
  ushort* Btx = (ushort*)alloc((size_t)384*768*2);
  ushort* Bth = (ushort*)alloc((size_t)128*384*2);
  float* bzc  = (float*)alloc(128*4);
  float* brc  = (float*)alloc(128*4);
  float* bhc  = (float*)alloc(128*4);
  float* dinv4= (float*)alloc((size_t)4*NN*4);
  int* deg4   = (int*)alloc((size_t)4*NN*4);
  int* cnt4   = (int*)alloc((size_t)4*NN*4);      // aliased as cur4 after scanA
  int* offs4  = (int*)alloc((size_t)4*(NN+1)*4);
  int* part4  = (int*)alloc((size_t)4*256*4);
  int2* meta4 = (int2*)alloc((size_t)4*EE*8);
  int* cur4 = cnt4;  // cnt consumed by scanA before scanC writes cur

  const int eb = (EE+255)/256;
  const int fb = (NN*FF+255)/256;
  const int sg = (NN+3)/4;
  const int MT = (NN+127)/128;  // 391

  // ---- one-time prep: weights, biases, all-step CSR ----
  k_packx<<<(384*768+255)/256,256,0,stream>>>(Wxz,Wxr,Wxh,Whz,Whr,Btx);
  k_packh<<<(128*384+255)/256,256,0,stream>>>(Whh,Bth);
  k_bias<<<1,384,0,stream>>>(bxz,bhz,bxr,bhr,bxh,bhh,bzc,brc,bhc);
  k_cast4<<<(TT*NN*FF/4+255)/256,256,0,stream>>>(x, xtb4, TT*NN*FF/4);
  k_zero_i<<<(8*NN+255)/256,256,0,stream>>>(deg4, 8*NN);  // deg4+cnt4 contiguous
  dim3 ge(eb,4), gn(NBS,4);
  k_count4<<<ge,256,0,stream>>>(ei, deg4, cnt4);
  k_scanA<<<gn,256,0,stream>>>(cnt4, offs4, part4);
  k_scanB<<<4,256,0,stream>>>(part4);
  k_scanC<<<gn,256,0,stream>>>(deg4, offs4, part4, dinv4, cur4);
  k_scatter4<<<ge,256,0,stream>>>(ei, dinv4, offs4, cur4, meta4);

  float* Hc = Ha; float* Hn = Hb;
  ushort* Hcb = Hab; ushort* Hnb = Hbb;
  for(int t=0;t<TT;++t){
    const ushort* xtb = xtb4 + (size_t)t*NN*FF;
    const int* offs = offs4 + (size_t)t*(NN+1);
    const int2* meta = meta4 + (size_t)t*EE;
    if(t==0){
      // H == 0: x-path only; gates z,h only
      k_spmm1<<<sg,256,0,stream>>>(offs,meta, xtb, nullptr, A1b);
      k_spmm1<<<sg,256,0,stream>>>(offs,meta, A1b, xtb,     A2b);
      dim3 g0(MT,2);
      k_mgemm<<<g0,256,0,stream>>>(xtb,A1b,A2b,nullptr,nullptr,nullptr,
          Btx, OX, 384, 768, 2, 0, 0);
      k_gru0<<<fb,256,0,stream>>>(OX, bzc, bhc, Hn, Hnb);
    } else {
      k_spmm2<<<sg,256,0,stream>>>(offs,meta, xtb,Hcb, nullptr,nullptr, A1b,A3b);
      k_spmm2<<<sg,256,0,stream>>>(offs,meta, A1b,A3b, xtb,Hcb,         A2b,A4b);
      dim3 g1(MT,3);
      k_mgemm<<<g1,256,0,stream>>>(xtb,A1b,A2b,Hcb,A3b,A4b,
          Btx, OX, 768, 768, 1, 0, 0);
      k_combA<<<fb,256,0,stream>>>(OX,Hc,bzc,brc,Zb,HRb);
      k_spmm1<<<sg,256,0,stream>>>(offs,meta, HRb, nullptr, A3b);
      k_spmm1<<<sg,256,0,stream>>>(offs,meta, A3b, HRb,     A4b);
      dim3 g3(MT,1);
      k_mgemm<<<g3,256,0,stream>>>(HRb,A3b,A4b,nullptr,nullptr,nullptr,
          Bth, OX, 384, 384, 1, 256, 1);
      k_combB<<<fb,256,0,stream>>>(OX,Zb,Hc,bhc,Hn,Hnb);
    }
    float* tmp=Hc; Hc=Hn; Hn=tmp;
    ushort* tb=Hcb; Hcb=Hnb; Hnb=tb;
  }
  // decoder: x_pred = relu(H@Wd1+bd1)@Wd2+bd2  (fp32); OX reused as temp
  dim3 gd((NN+63)/64, 2);
  k_gemm<<<gd,256,0,stream>>>(Hc, Wd1, OX, 128, 128, 128, bd1, 1);
  k_gemm<<<gd,256,0,stream>>>(OX, Wd2, out, 128, 128, 128, bd2, 0);
  k_copy<<<fb,256,0,stream>>>(Hc, out + (size_t)NN*FF, NN*FF);
}

// Round 6
// 1585.434 us; speedup vs baseline: 1.1737x; 1.0056x over previous
//
#include <hip/hip_runtime.h>
#include <math.h>

#define NN 50000
#define TT 4
#define FF 128
#define EE 800000
#define NBS 196   // scan blocks = ceil(NN/256)
#define NREP 8    // histogram replicas (one per XCD)

typedef __attribute__((ext_vector_type(8))) short bf8_t;
typedef __attribute__((ext_vector_type(4))) float f4_t;
typedef __attribute__((ext_vector_type(8))) ushort us8;

__device__ inline ushort f2bf(float f){
  union { float f; unsigned u; } v; v.f = f;
  unsigned u = v.u;
  unsigned r = (u + 0x7fff + ((u>>16)&1)) >> 16;  // RNE
  return (ushort)r;
}
__device__ inline float lo16(unsigned u){ union{unsigned u;float f;}v; v.u=u<<16; return v.f; }
__device__ inline float hi16(unsigned u){ union{unsigned u;float f;}v; v.u=u&0xffff0000u; return v.f; }
__device__ inline unsigned packbf(float x, float y){
  return (unsigned)f2bf(x) | ((unsigned)f2bf(y)<<16);
}
__device__ inline float sigm(float x){ return 1.f/(1.f+expf(-x)); }

// ---------------- utility ----------------
__global__ void k_zero_i(int* __restrict__ a, int n){
  int i = blockIdx.x*256 + threadIdx.x;
  if(i<n) a[i]=0;
}
// cast all T snapshots at once
__global__ void k_cast4(const float* __restrict__ in, ushort* __restrict__ outp, int n4){
  int i = blockIdx.x*256 + threadIdx.x;
  if(i<n4){
    float4 v = ((const float4*)in)[i];
    ushort4 o; o.x=f2bf(v.x); o.y=f2bf(v.y); o.z=f2bf(v.z); o.w=f2bf(v.w);
    ((ushort4*)outp)[i]=o;
  }
}
// combined biases: bz=bxz+bhz, br=bxr+bhr, bh=bxh+bhh
__global__ void k_bias(const float* bxz, const float* bhz, const float* bxr,
                       const float* bhr, const float* bxh, const float* bhh,
                       float* __restrict__ bz, float* __restrict__ br, float* __restrict__ bh){
  int i = threadIdx.x;  // 384 threads
  int c = i & 127, s = i >> 7;
  if(s==0) bz[c]=bxz[c]+bhz[c];
  else if(s==1) br[c]=bxr[c]+bhr[c];
  else bh[c]=bxh[c]+bhh[c];
}

// ---------- batched CSR build, XCD-replicated histograms (blockIdx.y = t) ----------
// deg8/cnt8 layout: [t][rep][NN]
__global__ void k_count8(const int* __restrict__ ei, int* __restrict__ deg8,
                         int* __restrict__ cnt8){
  int t = blockIdx.y;
  int rep = blockIdx.x & (NREP-1);   // round-robin block->XCD keeps replica in local L2
  int i = blockIdx.x*256 + threadIdx.x;
  const int* src = ei + (size_t)t*2*EE;
  const int* dst = src + EE;
  int* deg = deg8 + ((size_t)t*NREP + rep)*NN;
  int* cnt = cnt8 + ((size_t)t*NREP + rep)*NN;
  if(i<EE){ atomicAdd(&deg[src[i]],1); atomicAdd(&cnt[dst[i]],1); }
}
__global__ void k_scanA(const int* __restrict__ cnt8, int* __restrict__ offs4,
                        int* __restrict__ part4){
  int t = blockIdx.y;
  const int* cnt = cnt8 + (size_t)t*NREP*NN;
  int* offs = offs4 + (size_t)t*(NN+1);
  int* part = part4 + (size_t)t*256;
  __shared__ int sd[256];
  int b = blockIdx.x, tid = threadIdx.x, i = b*256+tid;
  int c = 0;
  if(i<NN){
    #pragma unroll
    for(int r=0;r<NREP;++r) c += cnt[(size_t)r*NN + i];
  }
  sd[tid]=c; __syncthreads();
  for(int off=1;off<256;off<<=1){
    int v=(tid>=off)?sd[tid-off]:0; __syncthreads();
    sd[tid]+=v; __syncthreads();
  }
  if(i<NN) offs[i]=sd[tid]-c;
  if(tid==255) part[b]=sd[255];
}
__global__ void k_scanB(int* __restrict__ part4){   // 4 blocks
  int* part = part4 + (size_t)blockIdx.x*256;
  __shared__ int sd[256];
  int tid = threadIdx.x;
  int v = (tid<NBS)?part[tid]:0;
  sd[tid]=v; __syncthreads();
  for(int off=1;off<256;off<<=1){
    int t=(tid>=off)?sd[tid-off]:0; __syncthreads();
    sd[tid]+=t; __syncthreads();
  }
  if(tid<NBS) part[tid]=sd[tid]-v;
}
// finalize offs; build per-replica absolute cursors; dinv from deg sum
__global__ void k_scanC(const int* __restrict__ deg8, const int* __restrict__ cnt8,
                        int* __restrict__ offs4, const int* __restrict__ part4,
                        float* __restrict__ dinv4, int* __restrict__ repcur8){
  int t = blockIdx.y;
  const int* deg = deg8 + (size_t)t*NREP*NN;
  const int* cnt = cnt8 + (size_t)t*NREP*NN;
  int* offs = offs4 + (size_t)t*(NN+1);
  const int* part = part4 + (size_t)t*256;
  float* dinv = dinv4 + (size_t)t*NN;
  int* repcur = repcur8 + (size_t)t*NREP*NN;
  int i = blockIdx.x*256 + threadIdx.x;
  if(i<NN){
    int base = offs[i] + part[blockIdx.x];
    offs[i] = base;
    int run = base, d = 0;
    #pragma unroll
    for(int r=0;r<NREP;++r){
      repcur[(size_t)r*NN + i] = run;
      run += cnt[(size_t)r*NN + i];
      d   += deg[(size_t)r*NN + i];
    }
    dinv[i] = d>0 ? rsqrtf((float)d) : 0.f;
  }
  if(i==0) offs[NN]=EE;
}
__global__ void k_scatter8(const int* __restrict__ ei, const float* __restrict__ dinv4,
                           int* __restrict__ repcur8, int2* __restrict__ meta4){
  int t = blockIdx.y;
  int rep = blockIdx.x & (NREP-1);   // MUST match k_count8's mapping
  int i = blockIdx.x*256 + threadIdx.x;
  const int* src = ei + (size_t)t*2*EE;
  const int* dst = src + EE;
  const float* dinv = dinv4 + (size_t)t*NN;
  int* cur = repcur8 + ((size_t)t*NREP + rep)*NN;
  int2* meta = meta4 + (size_t)t*EE;
  if(i<EE){
    int s=src[i], d=dst[i];
    float w = -dinv[s]*dinv[d];
    int pos = atomicAdd(&cur[d],1);
    int2 m; m.x=s; m.y=__float_as_int(w);
    meta[pos]=m;
  }
}

// -------- fused dual-input bf16 gather-SpMM --------
__global__ void k_spmm2(const int* __restrict__ offs, const int2* __restrict__ meta,
                        const ushort* __restrict__ Xa, const ushort* __restrict__ Xb,
                        const ushort* __restrict__ X0a, const ushort* __restrict__ X0b,
                        ushort* __restrict__ outA, ushort* __restrict__ outB){
  int wid = threadIdx.x>>6, lane = threadIdx.x&63;
  int row = blockIdx.x*4+wid;
  if(row>=NN) return;
  int beg = offs[row], end = offs[row+1];
  const unsigned* XA = (const unsigned*)Xa;
  const unsigned* XB = (const unsigned*)Xb;
  float ax=0.f, ay=0.f, bx=0.f, by=0.f;
  int e = beg;
  for(; e+3<end; e+=4){
    int2 p0=meta[e+0], p1=meta[e+1], p2=meta[e+2], p3=meta[e+3];
    float w0=__int_as_float(p0.y), w1=__int_as_float(p1.y);
    float w2=__int_as_float(p2.y), w3=__int_as_float(p3.y);
    unsigned a0=XA[p0.x*64+lane], a1=XA[p1.x*64+lane], a2=XA[p2.x*64+lane], a3=XA[p3.x*64+lane];
    unsigned b0=XB[p0.x*64+lane], b1=XB[p1.x*64+lane], b2=XB[p2.x*64+lane], b3=XB[p3.x*64+lane];
    ax=fmaf(w0,lo16(a0),ax); ay=fmaf(w0,hi16(a0),ay);
    ax=fmaf(w1,lo16(a1),ax); ay=fmaf(w1,hi16(a1),ay);
    ax=fmaf(w2,lo16(a2),ax); ay=fmaf(w2,hi16(a2),ay);
    ax=fmaf(w3,lo16(a3),ax); ay=fmaf(w3,hi16(a3),ay);
    bx=fmaf(w0,lo16(b0),bx); by=fmaf(w0,hi16(b0),by);
    bx=fmaf(w1,lo16(b1),bx); by=fmaf(w1,hi16(b1),by);
    bx=fmaf(w2,lo16(b2),bx); by=fmaf(w2,hi16(b2),by);
    bx=fmaf(w3,lo16(b3),bx); by=fmaf(w3,hi16(b3),by);
  }
  for(; e<end; ++e){
    int2 pm=meta[e]; float w=__int_as_float(pm.y);
    unsigned a=XA[pm.x*64+lane], b=XB[pm.x*64+lane];
    ax=fmaf(w,lo16(a),ax); ay=fmaf(w,hi16(a),ay);
    bx=fmaf(w,lo16(b),bx); by=fmaf(w,hi16(b),by);
  }
  int oi = row*64+lane;
  if(X0a){
    unsigned xa = ((const unsigned*)X0a)[oi];
    unsigned xb = ((const unsigned*)X0b)[oi];
    ax = 2.f*ax - lo16(xa); ay = 2.f*ay - hi16(xa);
    bx = 2.f*bx - lo16(xb); by = 2.f*by - hi16(xb);
  }
  ((unsigned*)outA)[oi] = packbf(ax, ay);
  ((unsigned*)outB)[oi] = packbf(bx, by);
}

// single-input variant
__global__ void k_spmm1(const int* __restrict__ offs, const int2* __restrict__ meta,
                        const ushort* __restrict__ Xa, const ushort* __restrict__ X0a,
                        ushort* __restrict__ outA){
  int wid = threadIdx.x>>6, lane = threadIdx.x&63;
  int row = blockIdx.x*4+wid;
  if(row>=NN) return;
  int beg = offs[row], end = offs[row+1];
  const unsigned* XA = (const unsigned*)Xa;
  float ax=0.f, ay=0.f;
  int e = beg;
  for(; e+3<end; e+=4){
    int2 p0=meta[e+0], p1=meta[e+1], p2=meta[e+2], p3=meta[e+3];
    float w0=__int_as_float(p0.y), w1=__int_as_float(p1.y);
    float w2=__int_as_float(p2.y), w3=__int_as_float(p3.y);
    unsigned a0=XA[p0.x*64+lane], a1=XA[p1.x*64+lane], a2=XA[p2.x*64+lane], a3=XA[p3.x*64+lane];
    ax=fmaf(w0,lo16(a0),ax); ay=fmaf(w0,hi16(a0),ay);
    ax=fmaf(w1,lo16(a1),ax); ay=fmaf(w1,hi16(a1),ay);
    ax=fmaf(w2,lo16(a2),ax); ay=fmaf(w2,hi16(a2),ay);
    ax=fmaf(w3,lo16(a3),ax); ay=fmaf(w3,hi16(a3),ay);
  }
  for(; e<end; ++e){
    int2 pm=meta[e]; float w=__int_as_float(pm.y);
    unsigned a=XA[pm.x*64+lane];
    ax=fmaf(w,lo16(a),ax); ay=fmaf(w,hi16(a),ay);
  }
  int oi = row*64+lane;
  if(X0a){
    unsigned xa = ((const unsigned*)X0a)[oi];
    ax = 2.f*ax - lo16(xa); ay = 2.f*ay - hi16(xa);
  }
  ((unsigned*)outA)[oi] = packbf(ax, ay);
}

// ---------------- MFMA bf16 GEMM (plain OX store, 2D grid) ----------------
__global__ __launch_bounds__(256) void k_mgemm(
    const ushort* __restrict__ A0, const ushort* __restrict__ A1,
    const ushort* __restrict__ A2, const ushort* __restrict__ A3,
    const ushort* __restrict__ A4, const ushort* __restrict__ A5,
    const ushort* __restrict__ Bt, float* __restrict__ C,
    int K, int ldb, int bnstep, int coloff, int beta)
{
  __shared__ ushort As[128*64];
  __shared__ ushort Bs[128*64];
  int tid = threadIdx.x;
  int lane = tid & 63;
  int wid = tid >> 6;
  int wr = (wid>>1)*64, wc = (wid&1)*64;
  int bm = blockIdx.x;
  int bn = blockIdx.y * bnstep;
  f4_t acc[4][4] = {};
  int srow = tid>>3, sc = tid&7;
  int lr = lane&15, lk = lane>>4;
  int nkt = K>>6;
  for(int kt=0; kt<nkt; ++kt){
    int k0 = kt<<6;
    const ushort* Ac = (k0<128)?A0:(k0<256)?A1:(k0<384)?A2:(k0<512)?A3:(k0<640)?A4:A5;
    int kloc = k0 & 127;
    #pragma unroll
    for(int p=0;p<4;++p){
      int r = srow + p*32;
      int gr = bm*128 + r; if(gr>=NN) gr=NN-1;
      us8 av = *(const us8*)(Ac + (size_t)gr*128 + kloc + sc*8);
      us8 bv = *(const us8*)(Bt + (size_t)(bn*128 + r)*ldb + k0 + sc*8);
      int wo = (r*128 + ((sc*16) ^ ((r&7)<<4))) >> 1;
      *(us8*)(As + wo) = av;
      *(us8*)(Bs + wo) = bv;
    }
    __syncthreads();
    #pragma unroll
    for(int kk=0;kk<2;++kk){
      bf8_t af[4], bfr[4];
      int co = kk*64 + lk*16;
      #pragma unroll
      for(int m=0;m<4;++m){
        int Ra = wr + m*16 + lr;
        af[m]  = *(const bf8_t*)(As + ((Ra*128 + (co ^ ((Ra&7)<<4)))>>1));
        int Rb = wc + m*16 + lr;
        bfr[m] = *(const bf8_t*)(Bs + ((Rb*128 + (co ^ ((Rb&7)<<4)))>>1));
      }
      #pragma unroll
      for(int m=0;m<4;++m)
        #pragma unroll
        for(int n=0;n<4;++n)
          acc[m][n] = __builtin_amdgcn_mfma_f32_16x16x32_bf16(af[m], bfr[n], acc[m][n], 0,0,0);
    }
    __syncthreads();
  }
  int row0 = bm*128 + wr + lk*4;
  int col0 = coloff + bn*128 + wc + lr;
  #pragma unroll
  for(int m=0;m<4;++m){
    #pragma unroll
    for(int i=0;i<4;++i){
      int r = row0 + m*16 + i;
      if(r<NN){
        float* cp = C + (size_t)r*384 + col0;
        #pragma unroll
        for(int n=0;n<4;++n){
          float v = acc[m][n][i];
          if(beta) v += cp[n*16];
          cp[n*16] = v;
        }
      }
    }
  }
}

// Z = sigmoid(OX[:,0:128]+bz); HRb = bf16(H * sigmoid(OX[:,128:256]+br))
__global__ void k_combA(const float* __restrict__ OX, const float* __restrict__ H,
                        const float* __restrict__ bz, const float* __restrict__ br,
                        float* __restrict__ Z, ushort* __restrict__ HRb){
  int i = blockIdx.x*256 + threadIdx.x;
  if(i>=NN*FF) return;
  int r = i>>7, c = i&127;
  float zv = sigm(OX[r*384+c]     + bz[c]);
  float rv = sigm(OX[r*384+128+c] + br[c]);
  float hr = H[i]*rv;
  Z[i]=zv; HRb[i]=f2bf(hr);
}

// Htilde = tanh(OX[:,256:384]+bh); Hnew = Z*H + (1-Z)*Htilde; optional 2nd fp32 copy
__global__ void k_combB(const float* __restrict__ OX, const float* __restrict__ Z,
                        const float* __restrict__ H, const float* __restrict__ bh,
                        float* __restrict__ Hn, ushort* __restrict__ Hnb,
                        float* __restrict__ Hout2){
  int i = blockIdx.x*256 + threadIdx.x;
  if(i>=NN*FF) return;
  int r = i>>7, c = i&127;
  float ht = tanhf(OX[r*384+256+c] + bh[c]);
  float z = Z[i];
  float hn = z*H[i] + (1.f-z)*ht;
  Hn[i] = hn; Hnb[i] = f2bf(hn);
  if(Hout2) Hout2[i] = hn;
}

// t=0 tail (H==0): Hn = (1 - sigm(OXz+bz)) * tanh(OXh+bh)
__global__ void k_gru0(const float* __restrict__ OX, const float* __restrict__ bz,
                       const float* __restrict__ bh, float* __restrict__ Hn,
                       ushort* __restrict__ Hnb){
  int i = blockIdx.x*256 + threadIdx.x;
  if(i>=NN*FF) return;
  int r = i>>7, c = i&127;
  float z  = sigm(OX[r*384+c] + bz[c]);
  float ht = tanhf(OX[r*384+256+c] + bh[c]);
  float hn = (1.f - z)*ht;
  Hn[i]=hn; Hnb[i]=f2bf(hn);
}

// fp32 GEMM for the (small) decoder
__global__ __launch_bounds__(256) void k_gemm(
    const float* __restrict__ A0, const float* __restrict__ B, float* __restrict__ C,
    int K, int Fo, int ldc, const float* __restrict__ bias, int act){
  __shared__ float Asq[64][17];
  __shared__ float Bsq[16][64];
  int tid = threadIdx.x;
  int tx = tid & 15, ty = tid >> 4;
  int bm = blockIdx.x, bn = blockIdx.y;
  float acc[4][4] = {{0.f}};
  int lr = tid>>2, lkv = tid&3;
  int lkk = tid>>4, lcv = tid&15;
  int arow = bm*64 + lr; if(arow >= NN) arow = NN-1;
  int nkb = K>>4;
  for(int kb=0; kb<nkb; ++kb){
    int koff = kb<<4;
    float4 av = *(const float4*)(A0 + arow*128 + koff + lkv*4);
    float4 bv = *(const float4*)(B + (koff+lkk)*Fo + bn*64 + lcv*4);
    Asq[lr][lkv*4+0]=av.x; Asq[lr][lkv*4+1]=av.y; Asq[lr][lkv*4+2]=av.z; Asq[lr][lkv*4+3]=av.w;
    *(float4*)(&Bsq[lkk][lcv*4]) = bv;
    __syncthreads();
    #pragma unroll
    for(int kk=0;kk<16;++kk){
      float a0=Asq[ty*4+0][kk], a1=Asq[ty*4+1][kk], a2=Asq[ty*4+2][kk], a3=Asq[ty*4+3][kk];
      float4 b = *(const float4*)(&Bsq[kk][tx*4]);
      acc[0][0]=fmaf(a0,b.x,acc[0][0]); acc[0][1]=fmaf(a0,b.y,acc[0][1]);
      acc[0][2]=fmaf(a0,b.z,acc[0][2]); acc[0][3]=fmaf(a0,b.w,acc[0][3]);
      acc[1][0]=fmaf(a1,b.x,acc[1][0]); acc[1][1]=fmaf(a1,b.y,acc[1][1]);
      acc[1][2]=fmaf(a1,b.z,acc[1][2]); acc[1][3]=fmaf(a1,b.w,acc[1][3]);
      acc[2][0]=fmaf(a2,b.x,acc[2][0]); acc[2][1]=fmaf(a2,b.y,acc[2][1]);
      acc[2][2]=fmaf(a2,b.z,acc[2][2]); acc[2][3]=fmaf(a2,b.w,acc[2][3]);
      acc[3][0]=fmaf(a3,b.x,acc[3][0]); acc[3][1]=fmaf(a3,b.y,acc[3][1]);
      acc[3][2]=fmaf(a3,b.z,acc[3][2]); acc[3][3]=fmaf(a3,b.w,acc[3][3]);
    }
    __syncthreads();
  }
  int row0 = bm*64 + ty*4;
  int col  = bn*64 + tx*4;
  #pragma unroll
  for(int i=0;i<4;++i){
    int r = row0+i;
    if(r<NN){
      float4 v; v.x=acc[i][0]; v.y=acc[i][1]; v.z=acc[i][2]; v.w=acc[i][3];
      if(bias){ v.x+=bias[col]; v.y+=bias[col+1]; v.z+=bias[col+2]; v.w+=bias[col+3]; }
      if(act){ v.x=fmaxf(v.x,0.f); v.y=fmaxf(v.y,0.f); v.z=fmaxf(v.z,0.f); v.w=fmaxf(v.w,0.f); }
      float* cp = C + r*ldc + col;
      *(float4*)cp = v;
    }
  }
}

// pack x-side weights transposed+concatenated: Btx[c][k], c in [0,384), k in [0,768)
__global__ void k_packx(const float* __restrict__ Wxz, const float* __restrict__ Wxr,
                        const float* __restrict__ Wxh, const float* __restrict__ Whz,
                        const float* __restrict__ Whr, ushort* __restrict__ Bt){
  int i = blockIdx.x*256 + threadIdx.x;
  if(i>=384*768) return;
  int c = i/768, k = i - c*768;
  int g = c>>7, j = c&127;
  int kb = k>>7, kk = k&127;
  float v;
  if(kb<3){
    const float* W = (g==0)?Wxz:((g==1)?Wxr:Wxh);
    v = W[(kb*128+kk)*128 + j];
  } else if(g<2){
    const float* W = (g==0)?Whz:Whr;
    v = W[((kb-3)*128+kk)*128 + j];
  } else v = 0.f;
  Bt[i] = f2bf(v);
}
// Bth[c][k] = Whh[k>>7][k&127][c], c<128, k<384
__global__ void k_packh(const float* __restrict__ Whh, ushort* __restrict__ Bt){
  int i = blockIdx.x*256 + threadIdx.x;
  if(i>=128*384) return;
  int c = i/384, k = i - c*384;
  Bt[i] = f2bf(Whh[((k>>7)*128 + (k&127))*128 + c]);
}

extern "C" void kernel_launch(void* const* d_in, const int* in_sizes, int n_in,
                              void* d_out, int out_size, void* d_ws, size_t ws_size,
                              hipStream_t stream) {
  const float* x   = (const float*)d_in[0];
  const int*   ei  = (const int*)d_in[1];
  const float* Wxz = (const float*)d_in[2];
  const float* Whz = (const float*)d_in[3];
  const float* Wxr = (const float*)d_in[4];
  const float* Whr = (const float*)d_in[5];
  const float* Wxh = (const float*)d_in[6];
  const float* Whh = (const float*)d_in[7];
  const float* bxz = (const float*)d_in[8];
  const float* bhz = (const float*)d_in[9];
  const float* bxr = (const float*)d_in[10];
  const float* bhr = (const float*)d_in[11];
  const float* bxh = (const float*)d_in[12];
  const float* bhh = (const float*)d_in[13];
  const float* Wd1 = (const float*)d_in[14];
  const float* bd1 = (const float*)d_in[15];
  const float* Wd2 = (const float*)d_in[16];
  const float* bd2 = (const float*)d_in[17];
  float* out = (float*)d_out;

  char* p = (char*)d_ws;
  auto alloc = [&](size_t bytes)->void*{ void* r = (void*)p; p += (bytes+255)&~(size_t)255; return r; };
  const size_t NFB  = (size_t)NN*FF*4;
  const size_t NFB2 = (size_t)NN*FF*2;
  float* Ha   = (float*)alloc(NFB);
  float* Hb   = (float*)alloc(NFB);
  float* OX   = (float*)alloc((size_t)NN*384*4);  // also decoder temp
  float* Zb   = (float*)alloc(NFB);
  ushort* xtb4= (ushort*)alloc(NFB2*TT);
  ushort* A1b = (ushort*)alloc(NFB2);
  ushort* A2b = (ushort*)alloc(NFB2);
  ushort* A3b = (ushort*)alloc(NFB2);
  ushort* A4b = (ushort*)alloc(NFB2);
  ushort* HRb = (ushort*)alloc(NFB2);
  ushort* Hab = (ushort*)alloc(NFB2);
  ushort* Hbb = (ushort*)alloc(NFB2);
  ushort* Btx = (ushort*)alloc((size_t)384*768*2);
  ushort* Bth = (ushort*)alloc((size_t)128*384*2);
  float* bzc  = (float*)alloc(128*4);
  float* brc  = (float*)alloc(128*4);
  float* bhc  = (float*)alloc(128*4);
  float* dinv4= (float*)alloc((size_t)TT*NN*4);
  int* hist8  = (int*)alloc((size_t)2*TT*NREP*NN*4);   // deg8 | cnt8 contiguous
  int* deg8   = hist8;
  int* cnt8   = hist8 + (size_t)TT*NREP*NN;
  int* repcur8= (int*)alloc((size_t)TT*NREP*NN*4);
  int* offs4  = (int*)alloc((size_t)TT*(NN+1)*4);
  int* part4  = (int*)alloc((size_t)TT*256*4);
  int2* meta4 = (int2*)alloc((size_t)TT*EE*8);

  const int eb = (EE+255)/256;
  const int fb = (NN*FF+255)/256;
  const int sg = (NN+3)/4;
  const int MT = (NN+127)/128;  // 391

  // ---- one-time prep: weights, biases, all-step CSR ----
  k_packx<<<(384*768+255)/256,256,0,stream>>>(Wxz,Wxr,Wxh,Whz,Whr,Btx);
  k_packh<<<(128*384+255)/256,256,0,stream>>>(Whh,Bth);
  k_bias<<<1,384,0,stream>>>(bxz,bhz,bxr,bhr,bxh,bhh,bzc,brc,bhc);
  k_cast4<<<(TT*NN*FF/4+255)/256,256,0,stream>>>(x, xtb4, TT*NN*FF/4);
  k_zero_i<<<(2*TT*NREP*NN+255)/256,256,0,stream>>>(hist8, 2*TT*NREP*NN);
  dim3 ge(eb,TT), gn(NBS,TT);
  k_count8<<<ge,256,0,stream>>>(ei, deg8, cnt8);
  k_scanA<<<gn,256,0,stream>>>(cnt8, offs4, part4);
  k_scanB<<<TT,256,0,stream>>>(part4);
  k_scanC<<<gn,256,0,stream>>>(deg8, cnt8, offs4, part4, dinv4, repcur8);
  k_scatter8<<<ge,256,0,stream>>>(ei, dinv4, repcur8, meta4);

  float* Hc = Ha; float* Hn = Hb;
  ushort* Hcb = Hab; ushort* Hnb = Hbb;
  for(int t=0;t<TT;++t){
    const ushort* xtb = xtb4 + (size_t)t*NN*FF;
    const int* offs = offs4 + (size_t)t*(NN+1);
    const int2* meta = meta4 + (size_t)t*EE;
    if(t==0){
      // H == 0: x-path only; gates z,h only
      k_spmm1<<<sg,256,0,stream>>>(offs,meta, xtb, nullptr, A1b);
      k_spmm1<<<sg,256,0,stream>>>(offs,meta, A1b, xtb,     A2b);
      dim3 g0(MT,2);
      k_mgemm<<<g0,256,0,stream>>>(xtb,A1b,A2b,nullptr,nullptr,nullptr,
          Btx, OX, 384, 768, 2, 0, 0);
      k_gru0<<<fb,256,0,stream>>>(OX, bzc, bhc, Hn, Hnb);
    } else {
      k_spmm2<<<sg,256,0,stream>>>(offs,meta, xtb,Hcb, nullptr,nullptr, A1b,A3b);
      k_spmm2<<<sg,256,0,stream>>>(offs,meta, A1b,A3b, xtb,Hcb,         A2b,A4b);
      dim3 g1(MT,3);
      k_mgemm<<<g1,256,0,stream>>>(xtb,A1b,A2b,Hcb,A3b,A4b,
          Btx, OX, 768, 768, 1, 0, 0);
      k_combA<<<fb,256,0,stream>>>(OX,Hc,bzc,brc,Zb,HRb);
      k_spmm1<<<sg,256,0,stream>>>(offs,meta, HRb, nullptr, A3b);
      k_spmm1<<<sg,256,0,stream>>>(offs,meta, A3b, HRb,     A4b);
      dim3 g3(MT,1);
      k_mgemm<<<g3,256,0,stream>>>(HRb,A3b,A4b,nullptr,nullptr,nullptr,
          Bth, OX, 384, 384, 1, 256, 1);
      // last step also writes fp32 H straight into out[NN*FF..)
      float* hout2 = (t==TT-1) ? (out + (size_t)NN*FF) : nullptr;
      k_combB<<<fb,256,0,stream>>>(OX,Zb,Hc,bhc,Hn,Hnb,hout2);
    }
    float* tmp=Hc; Hc=Hn; Hn=tmp;
    ushort* tb=Hcb; Hcb=Hnb; Hnb=tb;
  }
  // decoder: x_pred = relu(H@Wd1+bd1)@Wd2+bd2  (fp32); OX reused as temp
  dim3 gd((NN+63)/64, 2);
  k_gemm<<<gd,256,0,stream>>>(Hc, Wd1, OX, 128, 128, 128, bd1, 1);
  k_gemm<<<gd,256,0,stream>>>(OX, Wd2, out, 128, 128, 128, bd2, 0);
}

// Round 7
// 1432.168 us; speedup vs baseline: 1.2993x; 1.1070x over previous
//
#include <hip/hip_runtime.h>
#include <math.h>

#define NN 50000
#define TT 4
#define FF 128
#define EE 800000
#define NBS 196     // scan blocks = ceil(NN/256)
#define NSEG 4      // node-space segments for LDS histogram
#define BINSEG 12500
#define NCH 32      // edge chunks
#define CHUNK 25000 // EE/NCH

typedef __attribute__((ext_vector_type(8))) short bf8_t;
typedef __attribute__((ext_vector_type(4))) float f4_t;
typedef __attribute__((ext_vector_type(8))) ushort us8;

__device__ inline ushort f2bf(float f){
  union { float f; unsigned u; } v; v.f = f;
  unsigned u = v.u;
  unsigned r = (u + 0x7fff + ((u>>16)&1)) >> 16;  // RNE
  return (ushort)r;
}
__device__ inline float lo16(unsigned u){ union{unsigned u;float f;}v; v.u=u<<16; return v.f; }
__device__ inline float hi16(unsigned u){ union{unsigned u;float f;}v; v.u=u&0xffff0000u; return v.f; }
__device__ inline unsigned packbf(float x, float y){
  return (unsigned)f2bf(x) | ((unsigned)f2bf(y)<<16);
}
__device__ inline float sigm(float x){ return 1.f/(1.f+expf(-x)); }

// ---------------- utility ----------------
// cast all T snapshots at once
__global__ void k_cast4(const float* __restrict__ in, ushort* __restrict__ outp, int n4){
  int i = blockIdx.x*256 + threadIdx.x;
  if(i<n4){
    float4 v = ((const float4*)in)[i];
    ushort4 o; o.x=f2bf(v.x); o.y=f2bf(v.y); o.z=f2bf(v.z); o.w=f2bf(v.w);
    ((ushort4*)outp)[i]=o;
  }
}
// combined biases: bz=bxz+bhz, br=bxr+bhr, bh=bxh+bhh
__global__ void k_bias(const float* bxz, const float* bhz, const float* bxr,
                       const float* bhr, const float* bxh, const float* bhh,
                       float* __restrict__ bz, float* __restrict__ br, float* __restrict__ bh){
  int i = threadIdx.x;  // 384 threads
  int c = i & 127, s = i >> 7;
  if(s==0) bz[c]=bxz[c]+bhz[c];
  else if(s==1) br[c]=bxr[c]+bhr[c];
  else bh[c]=bxh[c]+bhh[c];
}

// ---------- CSR build: zero-global-atomic LDS histograms ----------
// grid (NCH, NSEG, 2*TT); z = t*2 + arr (arr0 = src->deg, arr1 = dst->cnt)
// partial layout: [(z*NSEG+seg)*NCH + c][BINSEG]
__global__ __launch_bounds__(256) void k_hist(const int* __restrict__ ei,
                                              int* __restrict__ part){
  int c = blockIdx.x, seg = blockIdx.y, z = blockIdx.z;
  int t = z >> 1, arr = z & 1;
  const int* keys = ei + (size_t)t*2*EE + (size_t)arr*EE;
  __shared__ int h[BINSEG];
  for(int i=threadIdx.x;i<BINSEG;i+=256) h[i]=0;
  __syncthreads();
  int base = seg*BINSEG;
  int e0 = c*CHUNK, e1 = e0+CHUNK;
  for(int e=e0+threadIdx.x; e<e1; e+=256){
    int k = keys[e] - base;
    if((unsigned)k < (unsigned)BINSEG) atomicAdd(&h[k],1);   // LDS atomic
  }
  __syncthreads();
  int* dp = part + ((((size_t)z)*NSEG + seg)*NCH + c)*BINSEG;
  for(int i=threadIdx.x;i<BINSEG;i+=256) dp[i]=h[i];
}
// merge partials -> deg4[t][n], cnt4[t][n]
__global__ void k_merge(const int* __restrict__ part, int* __restrict__ deg4,
                        int* __restrict__ cnt4){
  int t = blockIdx.y, arr = blockIdx.z;
  int n = blockIdx.x*256 + threadIdx.x;
  if(n>=NN) return;
  int seg = n / BINSEG, b = n - seg*BINSEG;
  const int* p = part + ((((size_t)(t*2+arr))*NSEG + seg)*NCH)*BINSEG + b;
  int s = 0;
  #pragma unroll
  for(int c=0;c<NCH;++c) s += p[(size_t)c*BINSEG];
  int* o = (arr ? cnt4 : deg4) + (size_t)t*NN;
  o[n] = s;
}

// ---------- hierarchical exclusive scan over cnt -> offs (blockIdx.y = t) ----------
__global__ void k_scanA(const int* __restrict__ cnt4, int* __restrict__ offs4,
                        int* __restrict__ part4){
  int t = blockIdx.y;
  const int* cnt = cnt4 + (size_t)t*NN;
  int* offs = offs4 + (size_t)t*(NN+1);
  int* part = part4 + (size_t)t*256;
  __shared__ int sd[256];
  int b = blockIdx.x, tid = threadIdx.x, i = b*256+tid;
  int c = (i<NN)?cnt[i]:0;
  sd[tid]=c; __syncthreads();
  for(int off=1;off<256;off<<=1){
    int v=(tid>=off)?sd[tid-off]:0; __syncthreads();
    sd[tid]+=v; __syncthreads();
  }
  if(i<NN) offs[i]=sd[tid]-c;
  if(tid==255) part[b]=sd[255];
}
__global__ void k_scanB(int* __restrict__ part4){   // TT blocks
  int* part = part4 + (size_t)blockIdx.x*256;
  __shared__ int sd[256];
  int tid = threadIdx.x;
  int v = (tid<NBS)?part[tid]:0;
  sd[tid]=v; __syncthreads();
  for(int off=1;off<256;off<<=1){
    int t=(tid>=off)?sd[tid-off]:0; __syncthreads();
    sd[tid]+=t; __syncthreads();
  }
  if(tid<NBS) part[tid]=sd[tid]-v;
}
__global__ void k_scanC(const int* __restrict__ deg4, int* __restrict__ offs4,
                        const int* __restrict__ part4, float* __restrict__ dinv4,
                        int* __restrict__ cur4){
  int t = blockIdx.y;
  const int* deg = deg4 + (size_t)t*NN;
  int* offs = offs4 + (size_t)t*(NN+1);
  const int* part = part4 + (size_t)t*256;
  float* dinv = dinv4 + (size_t)t*NN;
  int* cur = cur4 + (size_t)t*NN;
  int i = blockIdx.x*256 + threadIdx.x;
  if(i<NN){
    offs[i] += part[blockIdx.x];
    int d = deg[i];
    dinv[i] = d>0 ? rsqrtf((float)d) : 0.f;
    cur[i]=0;
  }
  if(i==0) offs[NN]=EE;
}
__global__ void k_scatter4(const int* __restrict__ ei, const float* __restrict__ dinv4,
                           const int* __restrict__ offs4, int* __restrict__ cur4,
                           int2* __restrict__ meta4){
  int t = blockIdx.y;
  int i = blockIdx.x*256 + threadIdx.x;
  const int* src = ei + (size_t)t*2*EE;
  const int* dst = src + EE;
  const float* dinv = dinv4 + (size_t)t*NN;
  const int* offs = offs4 + (size_t)t*(NN+1);
  int* cur = cur4 + (size_t)t*NN;
  int2* meta = meta4 + (size_t)t*EE;
  if(i<EE){
    int s=src[i], d=dst[i];
    float w = -dinv[s]*dinv[d];
    int pos = offs[d] + atomicAdd(&cur[d],1);
    int2 m; m.x=s; m.y=__float_as_int(w);
    meta[pos]=m;
  }
}

// -------- fused dual-input bf16 gather-SpMM --------
__global__ void k_spmm2(const int* __restrict__ offs, const int2* __restrict__ meta,
                        const ushort* __restrict__ Xa, const ushort* __restrict__ Xb,
                        const ushort* __restrict__ X0a, const ushort* __restrict__ X0b,
                        ushort* __restrict__ outA, ushort* __restrict__ outB){
  int wid = threadIdx.x>>6, lane = threadIdx.x&63;
  int row = blockIdx.x*4+wid;
  if(row>=NN) return;
  int beg = offs[row], end = offs[row+1];
  const unsigned* XA = (const unsigned*)Xa;
  const unsigned* XB = (const unsigned*)Xb;
  float ax=0.f, ay=0.f, bx=0.f, by=0.f;
  int e = beg;
  for(; e+3<end; e+=4){
    int2 p0=meta[e+0], p1=meta[e+1], p2=meta[e+2], p3=meta[e+3];
    float w0=__int_as_float(p0.y), w1=__int_as_float(p1.y);
    float w2=__int_as_float(p2.y), w3=__int_as_float(p3.y);
    unsigned a0=XA[p0.x*64+lane], a1=XA[p1.x*64+lane], a2=XA[p2.x*64+lane], a3=XA[p3.x*64+lane];
    unsigned b0=XB[p0.x*64+lane], b1=XB[p1.x*64+lane], b2=XB[p2.x*64+lane], b3=XB[p3.x*64+lane];
    ax=fmaf(w0,lo16(a0),ax); ay=fmaf(w0,hi16(a0),ay);
    ax=fmaf(w1,lo16(a1),ax); ay=fmaf(w1,hi16(a1),ay);
    ax=fmaf(w2,lo16(a2),ax); ay=fmaf(w2,hi16(a2),ay);
    ax=fmaf(w3,lo16(a3),ax); ay=fmaf(w3,hi16(a3),ay);
    bx=fmaf(w0,lo16(b0),bx); by=fmaf(w0,hi16(b0),by);
    bx=fmaf(w1,lo16(b1),bx); by=fmaf(w1,hi16(b1),by);
    bx=fmaf(w2,lo16(b2),bx); by=fmaf(w2,hi16(b2),by);
    bx=fmaf(w3,lo16(b3),bx); by=fmaf(w3,hi16(b3),by);
  }
  for(; e<end; ++e){
    int2 pm=meta[e]; float w=__int_as_float(pm.y);
    unsigned a=XA[pm.x*64+lane], b=XB[pm.x*64+lane];
    ax=fmaf(w,lo16(a),ax); ay=fmaf(w,hi16(a),ay);
    bx=fmaf(w,lo16(b),bx); by=fmaf(w,hi16(b),by);
  }
  int oi = row*64+lane;
  if(X0a){
    unsigned xa = ((const unsigned*)X0a)[oi];
    unsigned xb = ((const unsigned*)X0b)[oi];
    ax = 2.f*ax - lo16(xa); ay = 2.f*ay - hi16(xa);
    bx = 2.f*bx - lo16(xb); by = 2.f*by - hi16(xb);
  }
  ((unsigned*)outA)[oi] = packbf(ax, ay);
  ((unsigned*)outB)[oi] = packbf(bx, by);
}

// single-input variant
__global__ void k_spmm1(const int* __restrict__ offs, const int2* __restrict__ meta,
                        const ushort* __restrict__ Xa, const ushort* __restrict__ X0a,
                        ushort* __restrict__ outA){
  int wid = threadIdx.x>>6, lane = threadIdx.x&63;
  int row = blockIdx.x*4+wid;
  if(row>=NN) return;
  int beg = offs[row], end = offs[row+1];
  const unsigned* XA = (const unsigned*)Xa;
  float ax=0.f, ay=0.f;
  int e = beg;
  for(; e+3<end; e+=4){
    int2 p0=meta[e+0], p1=meta[e+1], p2=meta[e+2], p3=meta[e+3];
    float w0=__int_as_float(p0.y), w1=__int_as_float(p1.y);
    float w2=__int_as_float(p2.y), w3=__int_as_float(p3.y);
    unsigned a0=XA[p0.x*64+lane], a1=XA[p1.x*64+lane], a2=XA[p2.x*64+lane], a3=XA[p3.x*64+lane];
    ax=fmaf(w0,lo16(a0),ax); ay=fmaf(w0,hi16(a0),ay);
    ax=fmaf(w1,lo16(a1),ax); ay=fmaf(w1,hi16(a1),ay);
    ax=fmaf(w2,lo16(a2),ax); ay=fmaf(w2,hi16(a2),ay);
    ax=fmaf(w3,lo16(a3),ax); ay=fmaf(w3,hi16(a3),ay);
  }
  for(; e<end; ++e){
    int2 pm=meta[e]; float w=__int_as_float(pm.y);
    unsigned a=XA[pm.x*64+lane];
    ax=fmaf(w,lo16(a),ax); ay=fmaf(w,hi16(a),ay);
  }
  int oi = row*64+lane;
  if(X0a){
    unsigned xa = ((const unsigned*)X0a)[oi];
    ax = 2.f*ax - lo16(xa); ay = 2.f*ay - hi16(xa);
  }
  ((unsigned*)outA)[oi] = packbf(ax, ay);
}

// ---------------- MFMA bf16 GEMM ----------------
// 1D grid, bn-fastest ordering + bijective chunked XCD remap (T1):
// logical = xcd-chunked(blockIdx.x); bm = logical/ngrp; bn = (logical%ngrp)*bnstep.
__global__ __launch_bounds__(256) void k_mgemm(
    const ushort* __restrict__ A0, const ushort* __restrict__ A1,
    const ushort* __restrict__ A2, const ushort* __restrict__ A3,
    const ushort* __restrict__ A4, const ushort* __restrict__ A5,
    const ushort* __restrict__ Bt, float* __restrict__ C,
    int K, int ldb, int ngrp, int bnstep, int coloff, int beta, int nwg)
{
  __shared__ ushort As[128*64];
  __shared__ ushort Bs[128*64];
  int tid = threadIdx.x;
  int lane = tid & 63;
  int wid = tid >> 6;
  int wr = (wid>>1)*64, wc = (wid&1)*64;
  // bijective chunked XCD remap (m204): XCD x gets a contiguous logical range
  int bid = blockIdx.x;
  int q = nwg >> 3, r = nwg & 7;
  int xs = bid & 7, j = bid >> 3;
  int logical = xs*q + ((xs<r)?xs:r) + j;
  int bm = logical / ngrp;
  int bn = (logical - bm*ngrp) * bnstep;
  f4_t acc[4][4] = {};
  int srow = tid>>3, sc = tid&7;
  int lr = lane&15, lk = lane>>4;
  int nkt = K>>6;
  for(int kt=0; kt<nkt; ++kt){
    int k0 = kt<<6;
    const ushort* Ac = (k0<128)?A0:(k0<256)?A1:(k0<384)?A2:(k0<512)?A3:(k0<640)?A4:A5;
    int kloc = k0 & 127;
    #pragma unroll
    for(int p=0;p<4;++p){
      int rr = srow + p*32;
      int gr = bm*128 + rr; if(gr>=NN) gr=NN-1;
      us8 av = *(const us8*)(Ac + (size_t)gr*128 + kloc + sc*8);
      us8 bv = *(const us8*)(Bt + (size_t)(bn*128 + rr)*ldb + k0 + sc*8);
      int wo = (rr*128 + ((sc*16) ^ ((rr&7)<<4))) >> 1;
      *(us8*)(As + wo) = av;
      *(us8*)(Bs + wo) = bv;
    }
    __syncthreads();
    #pragma unroll
    for(int kk=0;kk<2;++kk){
      bf8_t af[4], bfr[4];
      int co = kk*64 + lk*16;
      #pragma unroll
      for(int m=0;m<4;++m){
        int Ra = wr + m*16 + lr;
        af[m]  = *(const bf8_t*)(As + ((Ra*128 + (co ^ ((Ra&7)<<4)))>>1));
        int Rb = wc + m*16 + lr;
        bfr[m] = *(const bf8_t*)(Bs + ((Rb*128 + (co ^ ((Rb&7)<<4)))>>1));
      }
      #pragma unroll
      for(int m=0;m<4;++m)
        #pragma unroll
        for(int n=0;n<4;++n)
          acc[m][n] = __builtin_amdgcn_mfma_f32_16x16x32_bf16(af[m], bfr[n], acc[m][n], 0,0,0);
    }
    __syncthreads();
  }
  int row0 = bm*128 + wr + lk*4;
  int col0 = coloff + bn*128 + wc + lr;
  #pragma unroll
  for(int m=0;m<4;++m){
    #pragma unroll
    for(int i=0;i<4;++i){
      int rI = row0 + m*16 + i;
      if(rI<NN){
        float* cp = C + (size_t)rI*384 + col0;
        #pragma unroll
        for(int n=0;n<4;++n){
          float v = acc[m][n][i];
          if(beta) v += cp[n*16];
          cp[n*16] = v;
        }
      }
    }
  }
}

// Z = sigmoid(OX[:,0:128]+bz); HRb = bf16(H * sigmoid(OX[:,128:256]+br))
__global__ void k_combA(const float* __restrict__ OX, const float* __restrict__ H,
                        const float* __restrict__ bz, const float* __restrict__ br,
                        float* __restrict__ Z, ushort* __restrict__ HRb){
  int i = blockIdx.x*256 + threadIdx.x;
  if(i>=NN*FF) return;
  int r = i>>7, c = i&127;
  float zv = sigm(OX[r*384+c]     + bz[c]);
  float rv = sigm(OX[r*384+128+c] + br[c]);
  float hr = H[i]*rv;
  Z[i]=zv; HRb[i]=f2bf(hr);
}

// Htilde = tanh(OX[:,256:384]+bh); Hnew = Z*H + (1-Z)*Htilde; optional 2nd fp32 copy
__global__ void k_combB(const float* __restrict__ OX, const float* __restrict__ Z,
                        const float* __restrict__ H, const float* __restrict__ bh,
                        float* __restrict__ Hn, ushort* __restrict__ Hnb,
                        float* __restrict__ Hout2){
  int i = blockIdx.x*256 + threadIdx.x;
  if(i>=NN*FF) return;
  int r = i>>7, c = i&127;
  float ht = tanhf(OX[r*384+256+c] + bh[c]);
  float z = Z[i];
  float hn = z*H[i] + (1.f-z)*ht;
  Hn[i] = hn; Hnb[i] = f2bf(hn);
  if(Hout2) Hout2[i] = hn;
}

// t=0 tail (H==0): Hn = (1 - sigm(OXz+bz)) * tanh(OXh+bh)
__global__ void k_gru0(const float* __restrict__ OX, const float* __restrict__ bz,
                       const float* __restrict__ bh, float* __restrict__ Hn,
                       ushort* __restrict__ Hnb){
  int i = blockIdx.x*256 + threadIdx.x;
  if(i>=NN*FF) return;
  int r = i>>7, c = i&127;
  float z  = sigm(OX[r*384+c] + bz[c]);
  float ht = tanhf(OX[r*384+256+c] + bh[c]);
  float hn = (1.f - z)*ht;
  Hn[i]=hn; Hnb[i]=f2bf(hn);
}

// fp32 GEMM for the (small) decoder
__global__ __launch_bounds__(256) void k_gemm(
    const float* __restrict__ A0, const float* __restrict__ B, float* __restrict__ C,
    int K, int Fo, int ldc, const float* __restrict__ bias, int act){
  __shared__ float Asq[64][17];
  __shared__ float Bsq[16][64];
  int tid = threadIdx.x;
  int tx = tid & 15, ty = tid >> 4;
  int bm = blockIdx.x, bn = blockIdx.y;
  float acc[4][4] = {{0.f}};
  int lr = tid>>2, lkv = tid&3;
  int lkk = tid>>4, lcv = tid&15;
  int arow = bm*64 + lr; if(arow >= NN) arow = NN-1;
  int nkb = K>>4;
  for(int kb=0; kb<nkb; ++kb){
    int koff = kb<<4;
    float4 av = *(const float4*)(A0 + arow*128 + koff + lkv*4);
    float4 bv = *(const float4*)(B + (koff+lkk)*Fo + bn*64 + lcv*4);
    Asq[lr][lkv*4+0]=av.x; Asq[lr][lkv*4+1]=av.y; Asq[lr][lkv*4+2]=av.z; Asq[lr][lkv*4+3]=av.w;
    *(float4*)(&Bsq[lkk][lcv*4]) = bv;
    __syncthreads();
    #pragma unroll
    for(int kk=0;kk<16;++kk){
      float a0=Asq[ty*4+0][kk], a1=Asq[ty*4+1][kk], a2=Asq[ty*4+2][kk], a3=Asq[ty*4+3][kk];
      float4 b = *(const float4*)(&Bsq[kk][tx*4]);
      acc[0][0]=fmaf(a0,b.x,acc[0][0]); acc[0][1]=fmaf(a0,b.y,acc[0][1]);
      acc[0][2]=fmaf(a0,b.z,acc[0][2]); acc[0][3]=fmaf(a0,b.w,acc[0][3]);
      acc[1][0]=fmaf(a1,b.x,acc[1][0]); acc[1][1]=fmaf(a1,b.y,acc[1][1]);
      acc[1][2]=fmaf(a1,b.z,acc[1][2]); acc[1][3]=fmaf(a1,b.w,acc[1][3]);
      acc[2][0]=fmaf(a2,b.x,acc[2][0]); acc[2][1]=fmaf(a2,b.y,acc[2][1]);
      acc[2][2]=fmaf(a2,b.z,acc[2][2]); acc[2][3]=fmaf(a2,b.w,acc[2][3]);
      acc[3][0]=fmaf(a3,b.x,acc[3][0]); acc[3][1]=fmaf(a3,b.y,acc[3][1]);
      acc[3][2]=fmaf(a3,b.z,acc[3][2]); acc[3][3]=fmaf(a3,b.w,acc[3][3]);
    }
    __syncthreads();
  }
  int row0 = bm*64 + ty*4;
  int col  = bn*64 + tx*4;
  #pragma unroll
  for(int i=0;i<4;++i){
    int r = row0+i;
    if(r<NN){
      float4 v; v.x=acc[i][0]; v.y=acc[i][1]; v.z=acc[i][2]; v.w=acc[i][3];
      if(bias){ v.x+=bias[col]; v.y+=bias[col+1]; v.z+=bias[col+2]; v.w+=bias[col+3]; }
      if(act){ v.x=fmaxf(v.x,0.f); v.y=fmaxf(v.y,0.f); v.z=fmaxf(v.z,0.f); v.w=fmaxf(v.w,0.f); }
      float* cp = C + r*ldc + col;
      *(float4*)cp = v;
    }
  }
}

// pack x-side weights transposed+concatenated: Btx[c][k], c in [0,384), k in [0,768)
__global__ void k_packx(const float* __restrict__ Wxz, const float* __restrict__ Wxr,
                        const float* __restrict__ Wxh, const float* __restrict__ Whz,
                        const float* __restrict__ Whr, ushort* __restrict__ Bt){
  int i = blockIdx.x*256 + threadIdx.x;
  if(i>=384*768) return;
  int c = i/768, k = i - c*768;
  int g = c>>7, j = c&127;
  int kb = k>>7, kk = k&127;
  float v;
  if(kb<3){
    const float* W = (g==0)?Wxz:((g==1)?Wxr:Wxh);
    v = W[(kb*128+kk)*128 + j];
  } else if(g<2){
    const float* W = (g==0)?Whz:Whr;
    v = W[((kb-3)*128+kk)*128 + j];
  } else v = 0.f;
  Bt[i] = f2bf(v);
}
// Bth[c][k] = Whh[k>>7][k&127][c], c<128, k<384
__global__ void k_packh(const float* __restrict__ Whh, ushort* __restrict__ Bt){
  int i = blockIdx.x*256 + threadIdx.x;
  if(i>=128*384) return;
  int c = i/384, k = i - c*384;
  Bt[i] = f2bf(Whh[((k>>7)*128 + (k&127))*128 + c]);
}

extern "C" void kernel_launch(void* const* d_in, const int* in_sizes, int n_in,
                              void* d_out, int out_size, void* d_ws, size_t ws_size,
                              hipStream_t stream) {
  const float* x   = (const float*)d_in[0];
  const int*   ei  = (const int*)d_in[1];
  const float* Wxz = (const float*)d_in[2];
  const float* Whz = (const float*)d_in[3];
  const float* Wxr = (const float*)d_in[4];
  const float* Whr = (const float*)d_in[5];
  const float* Wxh = (const float*)d_in[6];
  const float* Whh = (const float*)d_in[7];
  const float* bxz = (const float*)d_in[8];
  const float* bhz = (const float*)d_in[9];
  const float* bxr = (const float*)d_in[10];
  const float* bhr = (const float*)d_in[11];
  const float* bxh = (const float*)d_in[12];
  const float* bhh = (const float*)d_in[13];
  const float* Wd1 = (const float*)d_in[14];
  const float* bd1 = (const float*)d_in[15];
  const float* Wd2 = (const float*)d_in[16];
  const float* bd2 = (const float*)d_in[17];
  float* out = (float*)d_out;

  char* p = (char*)d_ws;
  auto alloc = [&](size_t bytes)->void*{ void* r = (void*)p; p += (bytes+255)&~(size_t)255; return r; };
  const size_t NFB  = (size_t)NN*FF*4;
  const size_t NFB2 = (size_t)NN*FF*2;
  float* Ha   = (float*)alloc(NFB);
  float* Hb   = (float*)alloc(NFB);   // contiguous with Ha (NFB % 256 == 0)
  float* OX   = (float*)alloc((size_t)NN*384*4);  // also decoder temp
  float* Zb   = (float*)alloc(NFB);
  ushort* xtb4= (ushort*)alloc(NFB2*TT);
  ushort* A1b = (ushort*)alloc(NFB2);
  ushort* A2b = (ushort*)alloc(NFB2);
  ushort* A3b = (ushort*)alloc(NFB2);
  ushort* A4b = (ushort*)alloc(NFB2);
  ushort* HRb = (ushort*)alloc(NFB2);
  ushort* Hab = (ushort*)alloc(NFB2);
  ushort* Hbb = (ushort*)alloc(NFB2);
  ushort* Btx = (ushort*)alloc((size_t)384*768*2);
  ushort* Bth = (ushort*)alloc((size_t)128*384*2);
  float* bzc  = (float*)alloc(128*4);
  float* brc  = (float*)alloc(128*4);
  float* bhc  = (float*)alloc(128*4);
  float* dinv4= (float*)alloc((size_t)TT*NN*4);
  int* deg4   = (int*)alloc((size_t)TT*NN*4);
  int* cnt4   = (int*)alloc((size_t)TT*NN*4);
  int* cur4   = (int*)alloc((size_t)TT*NN*4);
  int* offs4  = (int*)alloc((size_t)TT*(NN+1)*4);
  int* part4  = (int*)alloc((size_t)TT*256*4);
  int2* meta4 = (int2*)alloc((size_t)TT*EE*8);
  // 51.2 MB histogram partials alias Ha+Hb (dead until the GRU loop):
  // 2*TT*NSEG*NCH*BINSEG*4 = 51,200,000 B == 2*NFB exactly.
  int* partial = (int*)Ha;

  const int eb = (EE+255)/256;
  const int fb = (NN*FF+255)/256;
  const int sg = (NN+3)/4;
  const int MT = (NN+127)/128;  // 391

  // ---- one-time prep: weights, biases, all-step CSR ----
  k_packx<<<(384*768+255)/256,256,0,stream>>>(Wxz,Wxr,Wxh,Whz,Whr,Btx);
  k_packh<<<(128*384+255)/256,256,0,stream>>>(Whh,Bth);
  k_bias<<<1,384,0,stream>>>(bxz,bhz,bxr,bhr,bxh,bhh,bzc,brc,bhc);
  k_cast4<<<(TT*NN*FF/4+255)/256,256,0,stream>>>(x, xtb4, TT*NN*FF/4);
  dim3 gh(NCH, NSEG, 2*TT);
  k_hist<<<gh,256,0,stream>>>(ei, partial);
  dim3 gm((NN+255)/256, TT, 2);
  k_merge<<<gm,256,0,stream>>>(partial, deg4, cnt4);
  dim3 ge(eb,TT), gn(NBS,TT);
  k_scanA<<<gn,256,0,stream>>>(cnt4, offs4, part4);
  k_scanB<<<TT,256,0,stream>>>(part4);
  k_scanC<<<gn,256,0,stream>>>(deg4, offs4, part4, dinv4, cur4);
  k_scatter4<<<ge,256,0,stream>>>(ei, dinv4, offs4, cur4, meta4);

  float* Hc = Ha; float* Hn = Hb;
  ushort* Hcb = Hab; ushort* Hnb = Hbb;
  for(int t=0;t<TT;++t){
    const ushort* xtb = xtb4 + (size_t)t*NN*FF;
    const int* offs = offs4 + (size_t)t*(NN+1);
    const int2* meta = meta4 + (size_t)t*EE;
    if(t==0){
      // H == 0: x-path only; gates z,h only
      k_spmm1<<<sg,256,0,stream>>>(offs,meta, xtb, nullptr, A1b);
      k_spmm1<<<sg,256,0,stream>>>(offs,meta, A1b, xtb,     A2b);
      int nwg0 = MT*2;
      k_mgemm<<<nwg0,256,0,stream>>>(xtb,A1b,A2b,nullptr,nullptr,nullptr,
          Btx, OX, 384, 768, 2, 2, 0, 0, nwg0);
      k_gru0<<<fb,256,0,stream>>>(OX, bzc, bhc, Hn, Hnb);
    } else {
      k_spmm2<<<sg,256,0,stream>>>(offs,meta, xtb,Hcb, nullptr,nullptr, A1b,A3b);
      k_spmm2<<<sg,256,0,stream>>>(offs,meta, A1b,A3b, xtb,Hcb,         A2b,A4b);
      int nwg1 = MT*3;
      k_mgemm<<<nwg1,256,0,stream>>>(xtb,A1b,A2b,Hcb,A3b,A4b,
          Btx, OX, 768, 768, 3, 1, 0, 0, nwg1);
      k_combA<<<fb,256,0,stream>>>(OX,Hc,bzc,brc,Zb,HRb);
      k_spmm1<<<sg,256,0,stream>>>(offs,meta, HRb, nullptr, A3b);
      k_spmm1<<<sg,256,0,stream>>>(offs,meta, A3b, HRb,     A4b);
      int nwg3 = MT;
      k_mgemm<<<nwg3,256,0,stream>>>(HRb,A3b,A4b,nullptr,nullptr,nullptr,
          Bth, OX, 384, 384, 1, 1, 256, 1, nwg3);
      // last step also writes fp32 H straight into out[NN*FF..)
      float* hout2 = (t==TT-1) ? (out + (size_t)NN*FF) : nullptr;
      k_combB<<<fb,256,0,stream>>>(OX,Zb,Hc,bhc,Hn,Hnb,hout2);
    }
    float* tmp=Hc; Hc=Hn; Hn=tmp;
    ushort* tb=Hcb; Hcb=Hnb; Hnb=tb;
  }
  // decoder: x_pred = relu(H@Wd1+bd1)@Wd2+bd2  (fp32); OX reused as temp
  dim3 gd((NN+63)/64, 2);
  k_gemm<<<gd,256,0,stream>>>(Hc, Wd1, OX, 128, 128, 128, bd1, 1);
  k_gemm<<<gd,256,0,stream>>>(OX, Wd2, out, 128, 128, 128, bd2, 0);
}

// Round 8
// 1275.800 us; speedup vs baseline: 1.4585x; 1.1226x over previous
//
#include <hip/hip_runtime.h>
#include <math.h>

#define NN 50000
#define TT 4
#define FF 128
#define EE 800000
#define NSEG 4      // node-space segments for LDS deg histogram
#define BINSEG 12500
#define NCH 32      // edge chunks for deg histogram
#define CHUNK 25000
#define NCH2 128    // edge chunks for partition
#define CH2 6250    // EE/NCH2
#define NB2 64      // coarse dst buckets
#define CB 782      // nodes per bucket (64*782=50048 >= NN)
#define SMAX 13568  // LDS sort capacity per bucket (mean 12500, +9.5 sigma)

typedef __attribute__((ext_vector_type(8))) short bf8_t;
typedef __attribute__((ext_vector_type(4))) float f4_t;
typedef __attribute__((ext_vector_type(8))) ushort us8;

__device__ inline ushort f2bf(float f){
  union { float f; unsigned u; } v; v.f = f;
  unsigned u = v.u;
  unsigned r = (u + 0x7fff + ((u>>16)&1)) >> 16;  // RNE
  return (ushort)r;
}
__device__ inline float lo16(unsigned u){ union{unsigned u;float f;}v; v.u=u<<16; return v.f; }
__device__ inline float hi16(unsigned u){ union{unsigned u;float f;}v; v.u=u&0xffff0000u; return v.f; }
__device__ inline unsigned packbf(float x, float y){
  return (unsigned)f2bf(x) | ((unsigned)f2bf(y)<<16);
}
__device__ inline float sigm(float x){ return 1.f/(1.f+expf(-x)); }

// ---------------- utility ----------------
__global__ void k_cast4(const float* __restrict__ in, ushort* __restrict__ outp, int n4){
  int i = blockIdx.x*256 + threadIdx.x;
  if(i<n4){
    float4 v = ((const float4*)in)[i];
    ushort4 o; o.x=f2bf(v.x); o.y=f2bf(v.y); o.z=f2bf(v.z); o.w=f2bf(v.w);
    ((ushort4*)outp)[i]=o;
  }
}
__global__ void k_bias(const float* bxz, const float* bhz, const float* bxr,
                       const float* bhr, const float* bxh, const float* bhh,
                       float* __restrict__ bz, float* __restrict__ br, float* __restrict__ bh){
  int i = threadIdx.x;  // 384 threads
  int c = i & 127, s = i >> 7;
  if(s==0) bz[c]=bxz[c]+bhz[c];
  else if(s==1) br[c]=bxr[c]+bhr[c];
  else bh[c]=bxh[c]+bhh[c];
}

// ---------- deg (src) histogram via LDS segments -> dinv ----------
__global__ __launch_bounds__(256) void k_hist(const int* __restrict__ ei,
                                              int* __restrict__ part){
  int c = blockIdx.x, seg = blockIdx.y, t = blockIdx.z;
  const int* keys = ei + (size_t)t*2*EE;   // src array
  __shared__ int h[BINSEG];
  for(int i=threadIdx.x;i<BINSEG;i+=256) h[i]=0;
  __syncthreads();
  int base = seg*BINSEG;
  int e0 = c*CHUNK, e1 = e0+CHUNK;
  for(int e=e0+threadIdx.x; e<e1; e+=256){
    int k = keys[e] - base;
    if((unsigned)k < (unsigned)BINSEG) atomicAdd(&h[k],1);
  }
  __syncthreads();
  int* dp = part + ((((size_t)t)*NSEG + seg)*NCH + c)*BINSEG;
  for(int i=threadIdx.x;i<BINSEG;i+=256) dp[i]=h[i];
}
// merge partials -> dinv4[t][n]
__global__ void k_merge(const int* __restrict__ part, float* __restrict__ dinv4){
  int t = blockIdx.y;
  int n = blockIdx.x*256 + threadIdx.x;
  if(n>=NN) return;
  int seg = n / BINSEG, b = n - seg*BINSEG;
  const int* p = part + ((((size_t)t)*NSEG + seg)*NCH)*BINSEG + b;
  int s = 0;
  #pragma unroll
  for(int c=0;c<NCH;++c) s += p[(size_t)c*BINSEG];
  dinv4[(size_t)t*NN + n] = s>0 ? rsqrtf((float)s) : 0.f;
}

// ---------- coarse bucket counts per (t, chunk) ----------
__global__ __launch_bounds__(256) void k_ccount(const int* __restrict__ ei,
                                                int* __restrict__ ccnt){
  int c = blockIdx.x, t = blockIdx.y;
  const int* dst = ei + (size_t)t*2*EE + EE;
  __shared__ int h[NB2];
  if(threadIdx.x<NB2) h[threadIdx.x]=0;
  __syncthreads();
  int e0 = c*CH2, e1 = e0+CH2;
  for(int e=e0+threadIdx.x; e<e1; e+=256) atomicAdd(&h[dst[e]/CB],1);
  __syncthreads();
  if(threadIdx.x<NB2) ccnt[((size_t)t*NB2 + threadIdx.x)*NCH2 + c] = h[threadIdx.x];
}
// scan: Abase[t][b][c], Bbase[t][b], tot[t][b]   (one block per t, 128 threads)
__global__ __launch_bounds__(128) void k_cscan(const int* __restrict__ ccnt,
                        int* __restrict__ Abase, int* __restrict__ Bbase,
                        int* __restrict__ tot){
  int t = blockIdx.x, tid = threadIdx.x;
  __shared__ int st[NB2];
  __shared__ int sb[NB2];
  const int* cc = ccnt + (size_t)t*NB2*NCH2;
  if(tid<NB2){
    int s=0;
    for(int c=0;c<NCH2;++c) s += cc[tid*NCH2+c];
    st[tid]=s;
  }
  __syncthreads();
  if(tid==0){
    int run=0;
    for(int b=0;b<NB2;++b){ sb[b]=run; run+=st[b]; }
  }
  __syncthreads();
  if(tid<NB2){
    Bbase[t*NB2+tid]=sb[tid];
    tot[t*NB2+tid]=st[tid];
    int run = sb[tid];
    int* ab = Abase + ((size_t)t*NB2 + tid)*NCH2;
    for(int c=0;c<NCH2;++c){ ab[c]=run; run+=cc[tid*NCH2+c]; }
  }
}
// partition edges into bucket-contiguous staging (packed dstLocal<<16|src)
__global__ __launch_bounds__(256) void k_part(const int* __restrict__ ei,
                        const int* __restrict__ Abase, unsigned* __restrict__ staging){
  int c = blockIdx.x, t = blockIdx.y;
  const int* src = ei + (size_t)t*2*EE;
  const int* dst = src + EE;
  unsigned* stg = staging + (size_t)t*EE;
  const int* ab = Abase + (size_t)t*NB2*NCH2;
  __shared__ int h[NB2];
  if(threadIdx.x<NB2) h[threadIdx.x]=0;
  __syncthreads();
  int e0 = c*CH2, e1 = e0+CH2;
  for(int e=e0+threadIdx.x; e<e1; e+=256){
    int s=src[e], d=dst[e];
    int b = d/CB, dl = d - b*CB;
    int r = atomicAdd(&h[b],1);                 // LDS rank
    stg[ab[b*NCH2 + c] + r] = ((unsigned)dl<<16) | (unsigned)s;
  }
}
// per-bucket LDS counting sort -> meta (src,w) + offs
__global__ __launch_bounds__(256) void k_sortb(const unsigned* __restrict__ staging,
                        const int* __restrict__ Bbase, const int* __restrict__ tot,
                        const float* __restrict__ dinv4, int2* __restrict__ meta4,
                        int* __restrict__ offs4){
  int b = blockIdx.x, t = blockIdx.y, tid = threadIdx.x;
  __shared__ int cnt[784];
  __shared__ int sd[256];
  __shared__ unsigned sorted[SMAX];
  int sA = Bbase[t*NB2+b];
  int nb = tot[t*NB2+b];
  const unsigned* stg = staging + (size_t)t*EE + sA;
  const float* dinv = dinv4 + (size_t)t*NN;
  int* offs = offs4 + (size_t)t*(NN+1);
  int2* meta = meta4 + (size_t)t*EE + sA;
  for(int i=tid;i<784;i+=256) cnt[i]=0;
  __syncthreads();
  for(int i=tid;i<nb;i+=256) atomicAdd(&cnt[stg[i]>>16],1);
  __syncthreads();
  // exclusive scan of cnt[0..783]
  int runS = 0;
  for(int b0=0;b0<1024;b0+=256){
    int idx=b0+tid;
    int v = (idx<784)?cnt[idx]:0;
    __syncthreads();
    sd[tid]=v; __syncthreads();
    for(int off=1;off<256;off<<=1){
      int u=(tid>=off)?sd[tid-off]:0; __syncthreads();
      sd[tid]+=u; __syncthreads();
    }
    int incl = sd[tid];
    int tc = sd[255];
    if(idx<784) cnt[idx] = incl - v + runS;
    runS += tc;
    __syncthreads();
  }
  // write offs (coalesced); bins past NN-1 handled naturally (zero counts)
  for(int dl=tid; dl<CB; dl+=256){
    int n = b*CB + dl;
    if(n<=NN) offs[n] = sA + cnt[dl];
  }
  __syncthreads();
  // rank & LDS scatter
  for(int i=tid;i<nb;i+=256){
    unsigned v = stg[i];
    int r = atomicAdd(&cnt[v>>16],1);
    if(r<SMAX) sorted[r]=v;
  }
  __syncthreads();
  // coalesced output with weight computation
  for(int i=tid;i<nb;i+=256){
    if(i>=SMAX) break;
    unsigned v = sorted[i];
    int s = v & 0xFFFF;
    int d = b*CB + (v>>16);
    int2 m; m.x = s; m.y = __float_as_int(-dinv[s]*dinv[d]);
    meta[i]=m;
  }
}

// -------- fused dual-input bf16 gather-SpMM (pure L@X; recurrence folded into weights) --------
__global__ void k_spmm2(const int* __restrict__ offs, const int2* __restrict__ meta,
                        const ushort* __restrict__ Xa, const ushort* __restrict__ Xb,
                        ushort* __restrict__ outA, ushort* __restrict__ outB){
  int wid = threadIdx.x>>6, lane = threadIdx.x&63;
  int row = blockIdx.x*4+wid;
  if(row>=NN) return;
  int beg = offs[row], end = offs[row+1];
  const unsigned* XA = (const unsigned*)Xa;
  const unsigned* XB = (const unsigned*)Xb;
  float ax=0.f, ay=0.f, bx=0.f, by=0.f;
  int e = beg;
  for(; e+3<end; e+=4){
    int2 p0=meta[e+0], p1=meta[e+1], p2=meta[e+2], p3=meta[e+3];
    float w0=__int_as_float(p0.y), w1=__int_as_float(p1.y);
    float w2=__int_as_float(p2.y), w3=__int_as_float(p3.y);
    unsigned a0=XA[p0.x*64+lane], a1=XA[p1.x*64+lane], a2=XA[p2.x*64+lane], a3=XA[p3.x*64+lane];
    unsigned b0=XB[p0.x*64+lane], b1=XB[p1.x*64+lane], b2=XB[p2.x*64+lane], b3=XB[p3.x*64+lane];
    ax=fmaf(w0,lo16(a0),ax); ay=fmaf(w0,hi16(a0),ay);
    ax=fmaf(w1,lo16(a1),ax); ay=fmaf(w1,hi16(a1),ay);
    ax=fmaf(w2,lo16(a2),ax); ay=fmaf(w2,hi16(a2),ay);
    ax=fmaf(w3,lo16(a3),ax); ay=fmaf(w3,hi16(a3),ay);
    bx=fmaf(w0,lo16(b0),bx); by=fmaf(w0,hi16(b0),by);
    bx=fmaf(w1,lo16(b1),bx); by=fmaf(w1,hi16(b1),by);
    bx=fmaf(w2,lo16(b2),bx); by=fmaf(w2,hi16(b2),by);
    bx=fmaf(w3,lo16(b3),bx); by=fmaf(w3,hi16(b3),by);
  }
  for(; e<end; ++e){
    int2 pm=meta[e]; float w=__int_as_float(pm.y);
    unsigned a=XA[pm.x*64+lane], b=XB[pm.x*64+lane];
    ax=fmaf(w,lo16(a),ax); ay=fmaf(w,hi16(a),ay);
    bx=fmaf(w,lo16(b),bx); by=fmaf(w,hi16(b),by);
  }
  int oi = row*64+lane;
  ((unsigned*)outA)[oi] = packbf(ax, ay);
  ((unsigned*)outB)[oi] = packbf(bx, by);
}
__global__ void k_spmm1(const int* __restrict__ offs, const int2* __restrict__ meta,
                        const ushort* __restrict__ Xa, ushort* __restrict__ outA){
  int wid = threadIdx.x>>6, lane = threadIdx.x&63;
  int row = blockIdx.x*4+wid;
  if(row>=NN) return;
  int beg = offs[row], end = offs[row+1];
  const unsigned* XA = (const unsigned*)Xa;
  float ax=0.f, ay=0.f;
  int e = beg;
  for(; e+3<end; e+=4){
    int2 p0=meta[e+0], p1=meta[e+1], p2=meta[e+2], p3=meta[e+3];
    float w0=__int_as_float(p0.y), w1=__int_as_float(p1.y);
    float w2=__int_as_float(p2.y), w3=__int_as_float(p3.y);
    unsigned a0=XA[p0.x*64+lane], a1=XA[p1.x*64+lane], a2=XA[p2.x*64+lane], a3=XA[p3.x*64+lane];
    ax=fmaf(w0,lo16(a0),ax); ay=fmaf(w0,hi16(a0),ay);
    ax=fmaf(w1,lo16(a1),ax); ay=fmaf(w1,hi16(a1),ay);
    ax=fmaf(w2,lo16(a2),ax); ay=fmaf(w2,hi16(a2),ay);
    ax=fmaf(w3,lo16(a3),ax); ay=fmaf(w3,hi16(a3),ay);
  }
  for(; e<end; ++e){
    int2 pm=meta[e]; float w=__int_as_float(pm.y);
    unsigned a=XA[pm.x*64+lane];
    ax=fmaf(w,lo16(a),ax); ay=fmaf(w,hi16(a),ay);
  }
  ((unsigned*)outA)[row*64+lane] = packbf(ax, ay);
}

// ---------------- MFMA bf16 GEMM ----------------
__global__ __launch_bounds__(256) void k_mgemm(
    const ushort* __restrict__ A0, const ushort* __restrict__ A1,
    const ushort* __restrict__ A2, const ushort* __restrict__ A3,
    const ushort* __restrict__ A4, const ushort* __restrict__ A5,
    const ushort* __restrict__ Bt, float* __restrict__ C,
    int K, int ldb, int ngrp, int bnstep, int coloff, int beta, int nwg)
{
  __shared__ ushort As[128*64];
  __shared__ ushort Bs[128*64];
  int tid = threadIdx.x;
  int lane = tid & 63;
  int wid = tid >> 6;
  int wr = (wid>>1)*64, wc = (wid&1)*64;
  int bid = blockIdx.x;
  int q = nwg >> 3, r = nwg & 7;
  int xs = bid & 7, j = bid >> 3;
  int logical = xs*q + ((xs<r)?xs:r) + j;
  int bm = logical / ngrp;
  int bn = (logical - bm*ngrp) * bnstep;
  f4_t acc[4][4] = {};
  int srow = tid>>3, sc = tid&7;
  int lr = lane&15, lk = lane>>4;
  int nkt = K>>6;
  for(int kt=0; kt<nkt; ++kt){
    int k0 = kt<<6;
    const ushort* Ac = (k0<128)?A0:(k0<256)?A1:(k0<384)?A2:(k0<512)?A3:(k0<640)?A4:A5;
    int kloc = k0 & 127;
    #pragma unroll
    for(int p=0;p<4;++p){
      int rr = srow + p*32;
      int gr = bm*128 + rr; if(gr>=NN) gr=NN-1;
      us8 av = *(const us8*)(Ac + (size_t)gr*128 + kloc + sc*8);
      us8 bv = *(const us8*)(Bt + (size_t)(bn*128 + rr)*ldb + k0 + sc*8);
      int wo = (rr*128 + ((sc*16) ^ ((rr&7)<<4))) >> 1;
      *(us8*)(As + wo) = av;
      *(us8*)(Bs + wo) = bv;
    }
    __syncthreads();
    #pragma unroll
    for(int kk=0;kk<2;++kk){
      bf8_t af[4], bfr[4];
      int co = kk*64 + lk*16;
      #pragma unroll
      for(int m=0;m<4;++m){
        int Ra = wr + m*16 + lr;
        af[m]  = *(const bf8_t*)(As + ((Ra*128 + (co ^ ((Ra&7)<<4)))>>1));
        int Rb = wc + m*16 + lr;
        bfr[m] = *(const bf8_t*)(Bs + ((Rb*128 + (co ^ ((Rb&7)<<4)))>>1));
      }
      #pragma unroll
      for(int m=0;m<4;++m)
        #pragma unroll
        for(int n=0;n<4;++n)
          acc[m][n] = __builtin_amdgcn_mfma_f32_16x16x32_bf16(af[m], bfr[n], acc[m][n], 0,0,0);
    }
    __syncthreads();
  }
  int row0 = bm*128 + wr + lk*4;
  int col0 = coloff + bn*128 + wc + lr;
  #pragma unroll
  for(int m=0;m<4;++m){
    #pragma unroll
    for(int i=0;i<4;++i){
      int rI = row0 + m*16 + i;
      if(rI<NN){
        float* cp = C + (size_t)rI*384 + col0;
        #pragma unroll
        for(int n=0;n<4;++n){
          float v = acc[m][n][i];
          if(beta) v += cp[n*16];
          cp[n*16] = v;
        }
      }
    }
  }
}

__global__ void k_combA(const float* __restrict__ OX, const float* __restrict__ H,
                        const float* __restrict__ bz, const float* __restrict__ br,
                        float* __restrict__ Z, ushort* __restrict__ HRb){
  int i = blockIdx.x*256 + threadIdx.x;
  if(i>=NN*FF) return;
  int r = i>>7, c = i&127;
  float zv = sigm(OX[r*384+c]     + bz[c]);
  float rv = sigm(OX[r*384+128+c] + br[c]);
  float hr = H[i]*rv;
  Z[i]=zv; HRb[i]=f2bf(hr);
}
__global__ void k_combB(const float* __restrict__ OX, const float* __restrict__ Z,
                        const float* __restrict__ H, const float* __restrict__ bh,
                        float* __restrict__ Hn, ushort* __restrict__ Hnb,
                        float* __restrict__ Hout2){
  int i = blockIdx.x*256 + threadIdx.x;
  if(i>=NN*FF) return;
  int r = i>>7, c = i&127;
  float ht = tanhf(OX[r*384+256+c] + bh[c]);
  float z = Z[i];
  float hn = z*H[i] + (1.f-z)*ht;
  Hn[i] = hn; Hnb[i] = f2bf(hn);
  if(Hout2) Hout2[i] = hn;
}
__global__ void k_gru0(const float* __restrict__ OX, const float* __restrict__ bz,
                       const float* __restrict__ bh, float* __restrict__ Hn,
                       ushort* __restrict__ Hnb){
  int i = blockIdx.x*256 + threadIdx.x;
  if(i>=NN*FF) return;
  int r = i>>7, c = i&127;
  float z  = sigm(OX[r*384+c] + bz[c]);
  float ht = tanhf(OX[r*384+256+c] + bh[c]);
  float hn = (1.f - z)*ht;
  Hn[i]=hn; Hnb[i]=f2bf(hn);
}

// fp32 GEMM for the (small) decoder
__global__ __launch_bounds__(256) void k_gemm(
    const float* __restrict__ A0, const float* __restrict__ B, float* __restrict__ C,
    int K, int Fo, int ldc, const float* __restrict__ bias, int act){
  __shared__ float Asq[64][17];
  __shared__ float Bsq[16][64];
  int tid = threadIdx.x;
  int tx = tid & 15, ty = tid >> 4;
  int bm = blockIdx.x, bn = blockIdx.y;
  float acc[4][4] = {{0.f}};
  int lr = tid>>2, lkv = tid&3;
  int lkk = tid>>4, lcv = tid&15;
  int arow = bm*64 + lr; if(arow >= NN) arow = NN-1;
  int nkb = K>>4;
  for(int kb=0; kb<nkb; ++kb){
    int koff = kb<<4;
    float4 av = *(const float4*)(A0 + arow*128 + koff + lkv*4);
    float4 bv = *(const float4*)(B + (koff+lkk)*Fo + bn*64 + lcv*4);
    Asq[lr][lkv*4+0]=av.x; Asq[lr][lkv*4+1]=av.y; Asq[lr][lkv*4+2]=av.z; Asq[lr][lkv*4+3]=av.w;
    *(float4*)(&Bsq[lkk][lcv*4]) = bv;
    __syncthreads();
    #pragma unroll
    for(int kk=0;kk<16;++kk){
      float a0=Asq[ty*4+0][kk], a1=Asq[ty*4+1][kk], a2=Asq[ty*4+2][kk], a3=Asq[ty*4+3][kk];
      float4 b = *(const float4*)(&Bsq[kk][tx*4]);
      acc[0][0]=fmaf(a0,b.x,acc[0][0]); acc[0][1]=fmaf(a0,b.y,acc[0][1]);
      acc[0][2]=fmaf(a0,b.z,acc[0][2]); acc[0][3]=fmaf(a0,b.w,acc[0][3]);
      acc[1][0]=fmaf(a1,b.x,acc[1][0]); acc[1][1]=fmaf(a1,b.y,acc[1][1]);
      acc[1][2]=fmaf(a1,b.z,acc[1][2]); acc[1][3]=fmaf(a1,b.w,acc[1][3]);
      acc[2][0]=fmaf(a2,b.x,acc[2][0]); acc[2][1]=fmaf(a2,b.y,acc[2][1]);
      acc[2][2]=fmaf(a2,b.z,acc[2][2]); acc[2][3]=fmaf(a2,b.w,acc[2][3]);
      acc[3][0]=fmaf(a3,b.x,acc[3][0]); acc[3][1]=fmaf(a3,b.y,acc[3][1]);
      acc[3][2]=fmaf(a3,b.z,acc[3][2]); acc[3][3]=fmaf(a3,b.w,acc[3][3]);
    }
    __syncthreads();
  }
  int row0 = bm*64 + ty*4;
  int col  = bn*64 + tx*4;
  #pragma unroll
  for(int i=0;i<4;++i){
    int r = row0+i;
    if(r<NN){
      float4 v; v.x=acc[i][0]; v.y=acc[i][1]; v.z=acc[i][2]; v.w=acc[i][3];
      if(bias){ v.x+=bias[col]; v.y+=bias[col+1]; v.z+=bias[col+2]; v.w+=bias[col+3]; }
      if(act){ v.x=fmaxf(v.x,0.f); v.y=fmaxf(v.y,0.f); v.z=fmaxf(v.z,0.f); v.w=fmaxf(v.w,0.f); }
      float* cp = C + r*ldc + col;
      *(float4*)cp = v;
    }
  }
}

// pack x-side weights, REBASED: chunks [X:(W0-W2), U1:W1, U2:2*W2] for x and H sides
__global__ void k_packx(const float* __restrict__ Wxz, const float* __restrict__ Wxr,
                        const float* __restrict__ Wxh, const float* __restrict__ Whz,
                        const float* __restrict__ Whr, ushort* __restrict__ Bt){
  int i = blockIdx.x*256 + threadIdx.x;
  if(i>=384*768) return;
  int c = i/768, k = i - c*768;
  int g = c>>7, j = c&127;
  int kb = k>>7, kk = k&127;
  float v;
  int e = kk*128 + j;
  if(kb<3){
    const float* W = (g==0)?Wxz:((g==1)?Wxr:Wxh);
    v = (kb==0) ? (W[e] - W[2*16384 + e]) : (kb==1 ? W[16384 + e] : 2.f*W[2*16384 + e]);
  } else if(g<2){
    const float* W = (g==0)?Whz:Whr;
    int kb2 = kb-3;
    v = (kb2==0) ? (W[e] - W[2*16384 + e]) : (kb2==1 ? W[16384 + e] : 2.f*W[2*16384 + e]);
  } else v = 0.f;
  Bt[i] = f2bf(v);
}
// Bth[c][k], REBASED Whh
__global__ void k_packh(const float* __restrict__ Whh, ushort* __restrict__ Bt){
  int i = blockIdx.x*256 + threadIdx.x;
  if(i>=128*384) return;
  int c = i/384, k = i - c*384;
  int kb = k>>7, kk = k&127;
  int e = kk*128 + c;
  float v = (kb==0) ? (Whh[e] - Whh[2*16384 + e]) : (kb==1 ? Whh[16384 + e] : 2.f*Whh[2*16384 + e]);
  Bt[i] = f2bf(v);
}

extern "C" void kernel_launch(void* const* d_in, const int* in_sizes, int n_in,
                              void* d_out, int out_size, void* d_ws, size_t ws_size,
                              hipStream_t stream) {
  const float* x   = (const float*)d_in[0];
  const int*   ei  = (const int*)d_in[1];
  const float* Wxz = (const float*)d_in[2];
  const float* Whz = (const float*)d_in[3];
  const float* Wxr = (const float*)d_in[4];
  const float* Whr = (const float*)d_in[5];
  const float* Wxh = (const float*)d_in[6];
  const float* Whh = (const float*)d_in[7];
  const float* bxz = (const float*)d_in[8];
  const float* bhz = (const float*)d_in[9];
  const float* bxr = (const float*)d_in[10];
  const float* bhr = (const float*)d_in[11];
  const float* bxh = (const float*)d_in[12];
  const float* bhh = (const float*)d_in[13];
  const float* Wd1 = (const float*)d_in[14];
  const float* bd1 = (const float*)d_in[15];
  const float* Wd2 = (const float*)d_in[16];
  const float* bd2 = (const float*)d_in[17];
  float* out = (float*)d_out;

  char* p = (char*)d_ws;
  auto alloc = [&](size_t bytes)->void*{ void* r = (void*)p; p += (bytes+255)&~(size_t)255; return r; };
  const size_t NFB  = (size_t)NN*FF*4;
  const size_t NFB2 = (size_t)NN*FF*2;
  float* Ha   = (float*)alloc(NFB);
  float* Hb   = (float*)alloc(NFB);
  float* OX   = (float*)alloc((size_t)NN*384*4);
  float* Zb   = (float*)alloc(NFB);
  ushort* xtb4= (ushort*)alloc(NFB2*TT);
  ushort* A1b = (ushort*)alloc(NFB2);
  ushort* A2b = (ushort*)alloc(NFB2);
  ushort* A3b = (ushort*)alloc(NFB2);
  ushort* A4b = (ushort*)alloc(NFB2);
  ushort* HRb = (ushort*)alloc(NFB2);
  ushort* Hab = (ushort*)alloc(NFB2);
  ushort* Hbb = (ushort*)alloc(NFB2);
  ushort* Btx = (ushort*)alloc((size_t)384*768*2);
  ushort* Bth = (ushort*)alloc((size_t)128*384*2);
  float* bzc  = (float*)alloc(128*4);
  float* brc  = (float*)alloc(128*4);
  float* bhc  = (float*)alloc(128*4);
  float* dinv4= (float*)alloc((size_t)TT*NN*4);
  int* ccnt   = (int*)alloc((size_t)TT*NB2*NCH2*4);
  int* Abase  = (int*)alloc((size_t)TT*NB2*NCH2*4);
  int* Bbase  = (int*)alloc((size_t)TT*NB2*4);
  int* tot    = (int*)alloc((size_t)TT*NB2*4);
  int* offs4  = (int*)alloc((size_t)TT*(NN+1)*4);
  int2* meta4 = (int2*)alloc((size_t)TT*EE*8);
  // aliases: deg-hist partials (25.6MB == NFB) in Ha; staging (12.8MB) in Hb.
  // Both fully consumed before the GRU loop first writes Ha/Hb.
  int* partial = (int*)Ha;
  unsigned* staging = (unsigned*)Hb;

  const int fb = (NN*FF+255)/256;
  const int sg = (NN+3)/4;
  const int MT = (NN+127)/128;  // 391

  // ---- one-time prep ----
  k_packx<<<(384*768+255)/256,256,0,stream>>>(Wxz,Wxr,Wxh,Whz,Whr,Btx);
  k_packh<<<(128*384+255)/256,256,0,stream>>>(Whh,Bth);
  k_bias<<<1,384,0,stream>>>(bxz,bhz,bxr,bhr,bxh,bhh,bzc,brc,bhc);
  k_cast4<<<(TT*NN*FF/4+255)/256,256,0,stream>>>(x, xtb4, TT*NN*FF/4);
  dim3 gh(NCH, NSEG, TT);
  k_hist<<<gh,256,0,stream>>>(ei, partial);
  dim3 gm((NN+255)/256, TT);
  k_merge<<<gm,256,0,stream>>>(partial, dinv4);
  dim3 gc(NCH2, TT);
  k_ccount<<<gc,256,0,stream>>>(ei, ccnt);
  k_cscan<<<TT,128,0,stream>>>(ccnt, Abase, Bbase, tot);
  k_part<<<gc,256,0,stream>>>(ei, Abase, staging);
  dim3 gs(NB2, TT);
  k_sortb<<<gs,256,0,stream>>>(staging, Bbase, tot, dinv4, meta4, offs4);

  float* Hc = Ha; float* Hn = Hb;
  ushort* Hcb = Hab; ushort* Hnb = Hbb;
  for(int t=0;t<TT;++t){
    const ushort* xtb = xtb4 + (size_t)t*NN*FF;
    const int* offs = offs4 + (size_t)t*(NN+1);
    const int2* meta = meta4 + (size_t)t*EE;
    if(t==0){
      k_spmm1<<<sg,256,0,stream>>>(offs,meta, xtb, A1b);
      k_spmm1<<<sg,256,0,stream>>>(offs,meta, A1b, A2b);
      int nwg0 = MT*2;
      k_mgemm<<<nwg0,256,0,stream>>>(xtb,A1b,A2b,nullptr,nullptr,nullptr,
          Btx, OX, 384, 768, 2, 2, 0, 0, nwg0);
      k_gru0<<<fb,256,0,stream>>>(OX, bzc, bhc, Hn, Hnb);
    } else {
      k_spmm2<<<sg,256,0,stream>>>(offs,meta, xtb,Hcb, A1b,A3b);
      k_spmm2<<<sg,256,0,stream>>>(offs,meta, A1b,A3b, A2b,A4b);
      int nwg1 = MT*3;
      k_mgemm<<<nwg1,256,0,stream>>>(xtb,A1b,A2b,Hcb,A3b,A4b,
          Btx, OX, 768, 768, 3, 1, 0, 0, nwg1);
      k_combA<<<fb,256,0,stream>>>(OX,Hc,bzc,brc,Zb,HRb);
      k_spmm1<<<sg,256,0,stream>>>(offs,meta, HRb, A3b);
      k_spmm1<<<sg,256,0,stream>>>(offs,meta, A3b, A4b);
      int nwg3 = MT;
      k_mgemm<<<nwg3,256,0,stream>>>(HRb,A3b,A4b,nullptr,nullptr,nullptr,
          Bth, OX, 384, 384, 1, 1, 256, 1, nwg3);
      float* hout2 = (t==TT-1) ? (out + (size_t)NN*FF) : nullptr;
      k_combB<<<fb,256,0,stream>>>(OX,Zb,Hc,bhc,Hn,Hnb,hout2);
    }
    float* tmp=Hc; Hc=Hn; Hn=tmp;
    ushort* tb=Hcb; Hcb=Hnb; Hnb=tb;
  }
  // decoder (fp32); OX reused as temp
  dim3 gd((NN+63)/64, 2);
  k_gemm<<<gd,256,0,stream>>>(Hc, Wd1, OX, 128, 128, 128, bd1, 1);
  k_gemm<<<gd,256,0,stream>>>(OX, Wd2, out, 128, 128, 128, bd2, 0);
}